// Round 5
// baseline (591.771 us; speedup 1.0000x reference)
//
#include <hip/hip_runtime.h>

typedef __bf16 bf16_t;
typedef __attribute__((ext_vector_type(8))) __bf16 bf16x8;
typedef __attribute__((ext_vector_type(4))) __bf16 bf16x4;
typedef __attribute__((ext_vector_type(4))) float f32x4;

// async global->LDS, 16B per lane; dest = wave-uniform base + lane*16 (linear)
#define GLL16(gsrc, ldst) __builtin_amdgcn_global_load_lds( \
    (const __attribute__((address_space(1))) void*)(gsrc),  \
    (__attribute__((address_space(3))) void*)(ldst), 16, 0, 0)

// ---------------- dtype detect: 1 = bf16 inputs, 0 = fp32 inputs.
__global__ void detect_dtype(const unsigned short* __restrict__ ct, int* __restrict__ flag) {
    if (threadIdx.x == 0 && blockIdx.x == 0) {
        int ok = 1;
        for (int i = 0; i < 16; i++) {
            int e = (ct[256 + i] >> 7) & 0xFF;
            ok &= (e >= 80 && e <= 126) ? 1 : 0;
        }
        *flag = ok;
    }
}

// ---------------- scan: wave-aggregated partition (1 atomic per wave per bucket)
__global__ void scan_rows(const int* __restrict__ lvl2, const int* __restrict__ lvl1,
                          const int* __restrict__ lvl0, const int* __restrict__ third,
                          int* __restrict__ lists, int* __restrict__ cnts, int* __restrict__ inv) {
    int r = blockIdx.x * 256 + threadIdx.x;   // grid covers exactly 28672
    int slot, lr, base_t, base_b;
    const int* lvl;
    if (r < 16384)      { slot = 0; lr = r;         lvl = lvl2; base_t = 0;     base_b = 16384; }
    else if (r < 24576) { slot = 1; lr = r - 16384; lvl = lvl1; base_t = 32768; base_b = 40960; }
    else                { slot = 2; lr = r - 24576; lvl = lvl0; base_t = 49152; base_b = 53248; }
    int node = lvl[lr];
    int tern = third[node] >= 0 ? 1 : 0;
    if (slot == 0)      inv[node] = lr;
    else if (slot == 1) inv[node] = 16384 + lr;

    unsigned long long bt = __ballot(tern);
    unsigned long long bb = __ballot(!tern);
    int lane = threadIdx.x & 63;
    unsigned long long ltm = (1ull << lane) - 1ull;
    int post = __popcll(bt & ltm), posb = __popcll(bb & ltm);
    int baseT = 0, baseB = 0;
    if (lane == 0) {
        baseT = atomicAdd(&cnts[slot * 2 + 1], __popcll(bt));
        baseB = atomicAdd(&cnts[slot * 2 + 0], __popcll(bb));
    }
    baseT = __shfl(baseT, 0, 64);
    baseB = __shfl(baseB, 0, 64);
    lists[tern ? (base_t + baseT + post) : (base_b + baseB + posb)] = lr;
}

// ---------------- merged prep: op/comp -> bf16, weights -> swizzled packed layout
// pack: [K][N] -> [K/32][N][32] shorts, with 16B chunk g' = g ^ ((n>>1)&3)
__global__ void prep(const void* __restrict__ op_table, bf16_t* __restrict__ opb,
                     const void* __restrict__ comp_table, bf16_t* __restrict__ ctb,
                     const void* __restrict__ W1b, bf16_t* __restrict__ W1bp,
                     const void* __restrict__ W1t, bf16_t* __restrict__ W1tp,
                     const void* __restrict__ W2b, bf16_t* __restrict__ W2bp,
                     const void* __restrict__ W2t, bf16_t* __restrict__ W2tp,
                     const int* __restrict__ flagp) {
    int b = blockIdx.x, tid = threadIdx.x;
    int isbf = *flagp;
    if (b < 16) {
        int i = b * 256 + tid;
        opb[i] = isbf ? ((const bf16_t*)op_table)[i] : (bf16_t)((const float*)op_table)[i];
        return;
    }
    if (b < 2016) {
        int i = (b - 16) * 256 + tid;
        ctb[i] = isbf ? ((const bf16_t*)comp_table)[i] : (bf16_t)((const float*)comp_table)[i];
        return;
    }
    const void* src; bf16_t* dst; int e0, Nmask, Nshift;
    if (b < 3552)      { src = W1b; dst = W1bp; e0 = (b - 2016) * 256; Nmask = 511; Nshift = 9; }
    else if (b < 5600) { src = W1t; dst = W1tp; e0 = (b - 3552) * 256; Nmask = 511; Nshift = 9; }
    else if (b < 6112) { src = W2b; dst = W2bp; e0 = (b - 5600) * 256; Nmask = 255; Nshift = 8; }
    else               { src = W2t; dst = W2tp; e0 = (b - 6112) * 256; Nmask = 255; Nshift = 8; }
    int e = e0 + tid;
    bf16_t v = isbf ? ((const bf16_t*)src)[e] : (bf16_t)((const float*)src)[e];
    int n = e & Nmask, k = e >> Nshift;
    int kc = k >> 5, kl = k & 31;
    int gp = (kl >> 3) ^ ((n >> 1) & 3);
    dst[(size_t)(((kc << Nshift) + n) << 5) + (gp << 3) + (kl & 7)] = v;
}

__device__ __forceinline__ void load8f(const bf16_t* ne2, const void* ct, int isbf,
                                       int invn, int cidn, int q, float* o) {
    if (invn >= 0) {
        bf16x8 v = *(const bf16x8*)(ne2 + (size_t)invn * 256 + q);
        for (int z = 0; z < 8; z++) o[z] = (float)v[z];
    } else if (isbf) {
        bf16x8 v = *(const bf16x8*)((const bf16_t*)ct + (size_t)cidn * 256 + q);
        for (int z = 0; z < 8; z++) o[z] = (float)v[z];
    } else {
        const float* fp = (const float*)ct + (size_t)cidn * 256 + q;
        f32x4 a = *(const f32x4*)fp, b = *(const f32x4*)(fp + 4);
        for (int z = 0; z < 4; z++) { o[z] = a[z]; o[z + 4] = b[z]; }
    }
}

__device__ __forceinline__ float ldparam(const void* p, int i, int isbf) {
    return isbf ? (float)((const bf16_t*)p)[i] : ((const float*)p)[i];
}

// ---------------- fused level kernel, M=32 rows/block, 2 blocks/CU
// LDS map (69632 B):
//   [0,32768)      B1 slab (single buffer, GLL16 linear); GEMM2: B2 slab (16KB) overlays
//   [32768,65536)  H [32][512] bf16 chunk-swizzled; after GEMM2: R float[32][256] rotated
//   [65536,67584)  A chunk [32][32] bf16 (GLL16 linear, pre-swizzled source)
//   [67584,68864)  LN partials (A region dead after GEMM1)
// Staging: global_load_lds only (no dest registers -> no scratch possible).
// Weights pre-swizzled in global by prep; LDS stays linear; reads apply the XOR.
__global__ __launch_bounds__(256, 2) void fused_level(
    const int* __restrict__ list_t, const int* __restrict__ list_b,
    const int* __restrict__ cntpair, const int* __restrict__ lvl_idx,
    const int* __restrict__ op_ids, const int* __restrict__ lch,
    const int* __restrict__ rch, const int* __restrict__ tch,
    bf16_t* __restrict__ ne2, const bf16_t* __restrict__ opb,
    const void* __restrict__ ct, const bf16_t* __restrict__ ctb,
    const int* __restrict__ cid, const int* __restrict__ inv,
    const int* __restrict__ flagp,
    const bf16_t* __restrict__ W1tp, const void* __restrict__ b1t,
    const bf16_t* __restrict__ W2tp, const void* __restrict__ b2t,
    const bf16_t* __restrict__ W1bp, const void* __restrict__ b1b,
    const bf16_t* __restrict__ W2bp, const void* __restrict__ b2b,
    const void* __restrict__ gma, const void* __restrict__ bta,
    int slotBase, void* __restrict__ out)
{
    __shared__ __align__(1024) char smem[69632];

    const int tid = threadIdx.x;
    const int w = tid >> 6, lane = tid & 63, cc = lane & 15, qq = lane >> 4;
    const int gx = (cc >> 1) & 3;   // chunk XOR for packed-weight / A reads
    const int e7 = cc & 7;          // chunk XOR for H
    const int cnt_t = cntpair[1], cnt_b = cntpair[0];
    const int blocks_t = (cnt_t + 31) >> 5;
    int tern, base, cnt, K1c;
    const int* list;
    const bf16_t *W1p, *W2p;
    const void *b1, *b2;
    if ((int)blockIdx.x < blocks_t) {
        tern = 1; list = list_t; base = blockIdx.x * 32; cnt = cnt_t;
        W1p = W1tp; b1 = b1t; W2p = W2tp; b2 = b2t; K1c = 32;
    } else {
        tern = 0; list = list_b; base = (blockIdx.x - blocks_t) * 32; cnt = cnt_b;
        if (base >= cnt) return;
        W1p = W1bp; b1 = b1b; W2p = W2bp; b2 = b2b; K1c = 24;
    }
    const int act = min(32, cnt - base);
    const int isbf = *flagp;

    // ---- A-staging identity (tid<128): row = tid>>2, phys 16B chunk = tid&3
    const bf16_t *pp0 = opb, *pp1 = opb, *pp2 = opb, *pp3 = opb;
    int glA = 0;
    if (tid < 128) {
        int rowA = tid >> 2;
        glA = (tid & 3) ^ ((rowA >> 1) & 3);       // logical chunk this thread fetches
        int rA = list[base + min(rowA, act - 1)];
        int nodeA = lvl_idx[rA];
        pp0 = opb + (size_t)op_ids[nodeA] * 256;
        int a0 = lch[nodeA], a1 = rch[nodeA];
        int a2 = tern ? tch[nodeA] : a0;
        int iv0 = inv[a0], iv1 = inv[a1], iv2 = inv[a2];
        pp1 = iv0 >= 0 ? ne2 + (size_t)iv0 * 256 : ctb + (size_t)cid[a0] * 256;
        pp2 = iv1 >= 0 ? ne2 + (size_t)iv1 * 256 : ctb + (size_t)cid[a1] * 256;
        pp3 = iv2 >= 0 ? ne2 + (size_t)iv2 * 256 : ctb + (size_t)cid[a2] * 256;
    }

    // ---- residual identity: row ms = tid>>3, col group g4 = tid&7
    const int ms = tid >> 3, g4 = tid & 7;
    const int lr = list[base + min(ms, act - 1)];
    const int node = lvl_idx[lr];
    const int c0 = lch[node], c1 = rch[node];
    const int c2 = tern ? tch[node] : c0;
    int sInv[3] = {inv[c0], inv[c1], inv[c2]};
    int sCid[3];
    sCid[0] = sInv[0] < 0 ? cid[c0] : 0;
    sCid[1] = sInv[1] < 0 ? cid[c1] : 0;
    sCid[2] = sInv[2] < 0 ? cid[c2] : 0;

    auto stage1 = [&](int kc) {
        const char* srcb = (const char*)W1p + ((size_t)kc << 15);
        #pragma unroll
        for (int i = 0; i < 8; i++) {
            int off = ((i << 2) + w) << 10;
            GLL16(srcb + off + (lane << 4), smem + off);
        }
        if (w < 2) {            // A chunk: 128 lanes x 16B = 2KB, linear dest
            int colg = kc * 32 + glA * 8;
            int piece = colg >> 8, po = colg & 255;
            const bf16_t* s = pp0;
            s = piece == 1 ? pp1 : s;
            s = piece == 2 ? pp2 : s;
            s = piece == 3 ? pp3 : s;
            GLL16(s + po, smem + 65536 + (w << 10));
        }
    };
    auto stage2 = [&](int kc) {
        const char* srcb = (const char*)W2p + ((size_t)kc << 14);
        #pragma unroll
        for (int i = 0; i < 4; i++) {
            int off = ((i << 2) + w) << 10;
            GLL16(srcb + off + (lane << 4), smem + off);
        }
    };

    const f32x4 zf = {0.f, 0.f, 0.f, 0.f};
    f32x4 acc1[2][8];
    for (int m = 0; m < 2; m++) for (int j = 0; j < 8; j++) acc1[m][j] = zf;

    // ---------- GEMM1 (swapped operands): lane holds H[m*16+cc][(w+4j)*16+qq*4+r]
    for (int kc = 0; kc < K1c; kc++) {
        __syncthreads();            // slab free (previous chunk's reads done)
        stage1(kc);
        __syncthreads();            // implicit vmcnt(0): slab ready
        const bf16_t* as = (const bf16_t*)(smem + 65536);
        const bf16_t* bs = (const bf16_t*)smem;
        bf16x8 af[2];
        for (int m = 0; m < 2; m++)
            af[m] = *(const bf16x8*)(as + (m * 16 + cc) * 32 + ((qq ^ gx) << 3));
        for (int j = 0; j < 8; j++) {
            bf16x8 bv = *(const bf16x8*)(bs + ((w + 4 * j) * 16 + cc) * 32 + ((qq ^ gx) << 3));
            for (int m = 0; m < 2; m++)
                acc1[m][j] = __builtin_amdgcn_mfma_f32_16x16x32_bf16(bv, af[m], acc1[m][j], 0, 0, 0);
        }
    }
    __syncthreads();                // all reads of B1/A done; regions reusable

    // ---------- B2 slab 0 flies under bias + exact GELU -> H [32][512] chunk-swizzled
    stage2(0);
    {
        char* Hb = smem + 32768;
        for (int m = 0; m < 2; m++) {
            int row = m * 16 + cc;
            for (int j = 0; j < 8; j++) {
                bf16x4 hv;
                for (int r = 0; r < 4; r++) {
                    float v = acc1[m][j][r] + ldparam(b1, (w + 4 * j) * 16 + qq * 4 + r, isbf);
                    hv[r] = (bf16_t)(0.5f * v * (1.0f + erff(v * 0.70710678118654752f)));
                }
                int c16 = ((w + 4 * j) << 1) + (qq >> 1);
                *(bf16x4*)(Hb + (row << 10) + ((c16 ^ e7) << 4) + ((qq & 1) << 3)) = hv;
            }
        }
    }
    __syncthreads();                // B2 slab 0 + H ready

    // ---------- GEMM2: [32 x 512] @ [512 x 256]
    f32x4 acc2[2][4];
    for (int m = 0; m < 2; m++) for (int j = 0; j < 4; j++) acc2[m][j] = zf;
    for (int kc = 0; kc < 16; kc++) {
        if (kc) { __syncthreads(); stage2(kc); __syncthreads(); }
        const char* Hb = smem + 32768;
        const bf16_t* bs = (const bf16_t*)smem;
        bf16x8 af[2];
        for (int m = 0; m < 2; m++)
            af[m] = *(const bf16x8*)(Hb + ((m * 16 + cc) << 10) + ((((kc << 2) + qq) ^ e7) << 4));
        for (int j = 0; j < 4; j++) {
            bf16x8 bv = *(const bf16x8*)(bs + ((w + 4 * j) * 16 + cc) * 32 + ((qq ^ gx) << 3));
            for (int m = 0; m < 2; m++)
                acc2[m][j] = __builtin_amdgcn_mfma_f32_16x16x32_bf16(af[m], bv, acc2[m][j], 0, 0, 0);
        }
    }
    __syncthreads();                // last H reads done; H region reusable

    // ---------- residual gather -> R float[32][256] (overlays H), col rotated by row*4
    {
        float* Rf = (float*)(smem + 32768);
        int colb = g4 * 32;
        for (int i = 0; i < 4; i++) {
            int q = colb + i * 8;
            float lv[8], rv[8], tv[8];
            load8f(ne2, ct, isbf, sInv[0], sCid[0], q, lv);
            load8f(ne2, ct, isbf, sInv[1], sCid[1], q, rv);
            if (tern) load8f(ne2, ct, isbf, sInv[2], sCid[2], q, tv);
            f32x4 s0, s1;
            if (tern) {
                for (int z = 0; z < 4; z++) {
                    s0[z] = (lv[z] + rv[z] + tv[z]) * (1.0f / 3.0f);
                    s1[z] = (lv[z + 4] + rv[z + 4] + tv[z + 4]) * (1.0f / 3.0f);
                }
            } else {
                for (int z = 0; z < 4; z++) {
                    s0[z] = lv[z] + rv[z];
                    s1[z] = lv[z + 4] + rv[z + 4];
                }
            }
            *(f32x4*)(Rf + ms * 256 + ((q + ms * 4) & 255)) = s0;
            *(f32x4*)(Rf + ms * 256 + ((q + 4 + ms * 4) & 255)) = s1;
        }
    }
    __syncthreads();

    // ---------- x = gemm2 + b2 + R ; LayerNorm over 256 cols per row
    float* partS = (float*)(smem + 67584); // [4][32]
    float* partQ = partS + 128;            // [4][32]
    float* muA   = partQ + 128;            // [32]
    float* rsA   = muA + 32;               // [32]
    const float* Rf = (const float*)(smem + 32768);

    float b2f[4], gf[4], btf[4];
    for (int j = 0; j < 4; j++) {
        int col = (w + 4 * j) * 16 + cc;
        b2f[j] = ldparam(b2, col, isbf);
        gf[j] = ldparam(gma, col, isbf);
        btf[j] = ldparam(bta, col, isbf);
    }

    for (int m = 0; m < 2; m++) for (int r = 0; r < 4; r++) {
        int row = m * 16 + qq * 4 + r;
        float ps = 0.f, pq = 0.f;
        for (int j = 0; j < 4; j++) {
            int col = (w + 4 * j) * 16 + cc;
            float x = acc2[m][j][r] + b2f[j] + Rf[(row << 8) + ((col + row * 4) & 255)];
            acc2[m][j][r] = x;
            ps += x; pq += x * x;
        }
        for (int d = 1; d < 16; d <<= 1) {
            ps += __shfl_xor(ps, d, 64);
            pq += __shfl_xor(pq, d, 64);
        }
        if (cc == 0) { partS[w * 32 + row] = ps; partQ[w * 32 + row] = pq; }
    }
    __syncthreads();
    if (tid < 32) {
        float s  = partS[tid] + partS[32 + tid] + partS[64 + tid] + partS[96 + tid];
        float sq = partQ[tid] + partQ[32 + tid] + partQ[64 + tid] + partQ[96 + tid];
        float mu = s * (1.0f / 256.0f);
        float var = sq * (1.0f / 256.0f) - mu * mu;
        muA[tid] = mu;
        rsA[tid] = rsqrtf(fmaxf(var, 0.0f) + 1e-5f);
    }
    __syncthreads();

    for (int m = 0; m < 2; m++) for (int r = 0; r < 4; r++) {
        int row = m * 16 + qq * 4 + r;
        if (row >= act) continue;
        float mu = muA[row], rs = rsA[row];
        int lr2 = list[base + row];
        for (int j = 0; j < 4; j++) {
            int col = (w + 4 * j) * 16 + cc;
            float y = (acc2[m][j][r] - mu) * rs * gf[j] + btf[j];
            if (out) {
                if (isbf) ((bf16_t*)out)[(size_t)lr2 * 256 + col] = (bf16_t)y;
                else      ((float*)out)[(size_t)lr2 * 256 + col] = y;
            } else {
                ne2[(size_t)(slotBase + lr2) * 256 + col] = (bf16_t)y;
            }
        }
    }
}

extern "C" void kernel_launch(void* const* d_in, const int* in_sizes, int n_in,
                              void* d_out, int out_size, void* d_ws, size_t ws_size,
                              hipStream_t stream) {
    const int* cid    = (const int*)d_in[0];
    const int* opids  = (const int*)d_in[1];
    const int* lch    = (const int*)d_in[2];
    const int* rch    = (const int*)d_in[3];
    const int* tch    = (const int*)d_in[4];
    const int* lvl2   = (const int*)d_in[5];
    const int* lvl1   = (const int*)d_in[6];
    const int* lvl0   = (const int*)d_in[7];
    const void* comp_table = d_in[8];
    const void* op_table   = d_in[9];
    const void* W1b = d_in[10];
    const void* b1b = d_in[11];
    const void* W2b = d_in[12];
    const void* b2b = d_in[13];
    const void* W1t = d_in[14];
    const void* b1t = d_in[15];
    const void* W2t = d_in[16];
    const void* b2t = d_in[17];
    const void* gma = d_in[18];
    const void* bta = d_in[19];

    char* wsp = (char*)d_ws;
    bf16_t* ne2  = (bf16_t*)wsp;                 size_t off = 12582912; // 24576*256*2
    bf16_t* opb  = (bf16_t*)(wsp + off);         off += 8192;           // 16*256*2
    bf16_t* ctb  = (bf16_t*)(wsp + off);         off += 1024000;        // 2000*256*2
    bf16_t* W1bp = (bf16_t*)(wsp + off);         off += 786432;         // 768*512*2
    bf16_t* W1tp = (bf16_t*)(wsp + off);         off += 1048576;        // 1024*512*2
    bf16_t* W2bp = (bf16_t*)(wsp + off);         off += 262144;         // 512*256*2
    bf16_t* W2tp = (bf16_t*)(wsp + off);         off += 262144;
    int* inv   = (int*)(wsp + off);              off += 262144;         // 65536*4
    int* lists = (int*)(wsp + off);              off += 229376;         // 57344*4
    int* cnts  = (int*)(wsp + off);              off += 64;             // total ~15.7 MiB
    int* flag  = cnts + 8;

    hipMemsetAsync(cnts, 0, 64, stream);
    hipMemsetAsync(inv, 0xFF, 262144, stream);
    detect_dtype<<<1, 64, 0, stream>>>((const unsigned short*)comp_table, flag);
    scan_rows<<<112, 256, 0, stream>>>(lvl2, lvl1, lvl0, tch, lists, cnts, inv);
    prep<<<6624, 256, 0, stream>>>(op_table, opb, comp_table, ctb,
                                   W1b, W1bp, W1t, W1tp, W2b, W2bp, W2t, W2tp, flag);

    // level 2: lists t @0 / b @16384, cnts slot 0 -> slots base 0
    fused_level<<<513, 256, 0, stream>>>(lists + 0, lists + 16384, cnts + 0, lvl2,
        opids, lch, rch, tch, ne2, opb, comp_table, ctb, cid, inv, flag,
        W1tp, b1t, W2tp, b2t, W1bp, b1b, W2bp, b2b, gma, bta, 0, nullptr);
    // level 1: lists t @32768 / b @40960, cnts slot 1 -> slots base 16384
    fused_level<<<257, 256, 0, stream>>>(lists + 32768, lists + 40960, cnts + 2, lvl1,
        opids, lch, rch, tch, ne2, opb, comp_table, ctb, cid, inv, flag,
        W1tp, b1t, W2tp, b2t, W1bp, b1b, W2bp, b2b, gma, bta, 16384, nullptr);
    // level 0: lists t @49152 / b @53248, cnts slot 2 -> d_out
    fused_level<<<129, 256, 0, stream>>>(lists + 49152, lists + 53248, cnts + 4, lvl0,
        opids, lch, rch, tch, ne2, opb, comp_table, ctb, cid, inv, flag,
        W1tp, b1t, W2tp, b2t, W1bp, b1b, W2bp, b2b, gma, bta, 0, d_out);
}

// Round 6
// 481.381 us; speedup vs baseline: 1.2293x; 1.2293x over previous
//
#include <hip/hip_runtime.h>

typedef __bf16 bf16_t;
typedef __attribute__((ext_vector_type(8))) __bf16 bf16x8;
typedef __attribute__((ext_vector_type(4))) __bf16 bf16x4;
typedef __attribute__((ext_vector_type(4))) float f32x4;
typedef __attribute__((ext_vector_type(8))) unsigned short u16x8;
typedef __attribute__((ext_vector_type(4))) unsigned short u16x4;

// ---------------- dtype detect: 1 = bf16 inputs, 0 = fp32 inputs.
__global__ void detect_dtype(const unsigned short* __restrict__ ct, int* __restrict__ flag) {
    if (threadIdx.x == 0 && blockIdx.x == 0) {
        int ok = 1;
        for (int i = 0; i < 16; i++) {
            int e = (ct[256 + i] >> 7) & 0xFF;
            ok &= (e >= 80 && e <= 126) ? 1 : 0;
        }
        *flag = ok;
    }
}

// ---------------- scan: wave-aggregated partition (1 atomic per wave per bucket)
__global__ void scan_rows(const int* __restrict__ lvl2, const int* __restrict__ lvl1,
                          const int* __restrict__ lvl0, const int* __restrict__ third,
                          int* __restrict__ lists, int* __restrict__ cnts, int* __restrict__ inv) {
    int r = blockIdx.x * 256 + threadIdx.x;   // grid covers exactly 28672
    int slot, lr, base_t, base_b;
    const int* lvl;
    if (r < 16384)      { slot = 0; lr = r;         lvl = lvl2; base_t = 0;     base_b = 16384; }
    else if (r < 24576) { slot = 1; lr = r - 16384; lvl = lvl1; base_t = 32768; base_b = 40960; }
    else                { slot = 2; lr = r - 24576; lvl = lvl0; base_t = 49152; base_b = 53248; }
    int node = lvl[lr];
    int tern = third[node] >= 0 ? 1 : 0;
    if (slot == 0)      inv[node] = lr;
    else if (slot == 1) inv[node] = 16384 + lr;

    unsigned long long bt = __ballot(tern);
    unsigned long long bb = __ballot(!tern);
    int lane = threadIdx.x & 63;
    unsigned long long ltm = (1ull << lane) - 1ull;
    int post = __popcll(bt & ltm), posb = __popcll(bb & ltm);
    int baseT = 0, baseB = 0;
    if (lane == 0) {
        baseT = atomicAdd(&cnts[slot * 2 + 1], __popcll(bt));
        baseB = atomicAdd(&cnts[slot * 2 + 0], __popcll(bb));
    }
    baseT = __shfl(baseT, 0, 64);
    baseB = __shfl(baseB, 0, 64);
    lists[tern ? (base_t + baseT + post) : (base_b + baseB + posb)] = lr;
}

// ---------------- merged prep: op/comp -> bf16, weights -> swizzled packed layout
// pack: [K][N] -> [K/32][N][32] shorts, with 16B chunk g' = g ^ ((n>>1)&3)
__global__ void prep(const void* __restrict__ op_table, bf16_t* __restrict__ opb,
                     const void* __restrict__ comp_table, bf16_t* __restrict__ ctb,
                     const void* __restrict__ W1b, bf16_t* __restrict__ W1bp,
                     const void* __restrict__ W1t, bf16_t* __restrict__ W1tp,
                     const void* __restrict__ W2b, bf16_t* __restrict__ W2bp,
                     const void* __restrict__ W2t, bf16_t* __restrict__ W2tp,
                     const int* __restrict__ flagp) {
    int b = blockIdx.x, tid = threadIdx.x;
    int isbf = *flagp;
    if (b < 16) {
        int i = b * 256 + tid;
        opb[i] = isbf ? ((const bf16_t*)op_table)[i] : (bf16_t)((const float*)op_table)[i];
        return;
    }
    if (b < 2016) {
        int i = (b - 16) * 256 + tid;
        ctb[i] = isbf ? ((const bf16_t*)comp_table)[i] : (bf16_t)((const float*)comp_table)[i];
        return;
    }
    const void* src; bf16_t* dst; int e0, Nmask, Nshift;
    if (b < 3552)      { src = W1b; dst = W1bp; e0 = (b - 2016) * 256; Nmask = 511; Nshift = 9; }
    else if (b < 5600) { src = W1t; dst = W1tp; e0 = (b - 3552) * 256; Nmask = 511; Nshift = 9; }
    else if (b < 6112) { src = W2b; dst = W2bp; e0 = (b - 5600) * 256; Nmask = 255; Nshift = 8; }
    else               { src = W2t; dst = W2tp; e0 = (b - 6112) * 256; Nmask = 255; Nshift = 8; }
    int e = e0 + tid;
    bf16_t v = isbf ? ((const bf16_t*)src)[e] : (bf16_t)((const float*)src)[e];
    int n = e & Nmask, k = e >> Nshift;
    int kc = k >> 5, kl = k & 31;
    int gp = (kl >> 3) ^ ((n >> 1) & 3);
    dst[(size_t)(((kc << Nshift) + n) << 5) + (gp << 3) + (kl & 7)] = v;
}

__device__ __forceinline__ void load8f(const bf16_t* ne2, const void* ct, int isbf,
                                       int invn, int cidn, int q, float* o) {
    if (invn >= 0) {
        bf16x8 v = *(const bf16x8*)(ne2 + (size_t)invn * 256 + q);
        for (int z = 0; z < 8; z++) o[z] = (float)v[z];
    } else if (isbf) {
        bf16x8 v = *(const bf16x8*)((const bf16_t*)ct + (size_t)cidn * 256 + q);
        for (int z = 0; z < 8; z++) o[z] = (float)v[z];
    } else {
        const float* fp = (const float*)ct + (size_t)cidn * 256 + q;
        f32x4 a = *(const f32x4*)fp, b = *(const f32x4*)(fp + 4);
        for (int z = 0; z < 4; z++) { o[z] = a[z]; o[z + 4] = b[z]; }
    }
}

__device__ __forceinline__ float ldparam(const void* p, int i, int isbf) {
    return isbf ? (float)((const bf16_t*)p)[i] : ((const float*)p)[i];
}

// ---------------- fused level kernel, M=32 rows/block, 2 blocks/CU
// R0's staging skeleton (direct 16B load -> immediate ds_write, 2 barriers/chunk,
// no lambdas, no global_load_lds, no register tiles held across barriers) +
// R5's verified layouts (packed stride-32 pre-swizzled W, swapped GEMM1,
// vectorized chunk-swizzled H, swizzled A, rotated R).
// LDS map (69632 B):
//   [0,32768)      B1 slab [512][32] shorts; GEMM2: B2 slab [256][32] overlays
//   [32768,65536)  H [32][512] bf16 chunk-swizzled; after GEMM2: R float[32][256] rotated
//   [65536,67584)  A chunk [32][32] bf16 chunk-swizzled
//   [67584,68864)  LN partials
__global__ __launch_bounds__(256, 2) void fused_level(
    const int* __restrict__ list_t, const int* __restrict__ list_b,
    const int* __restrict__ cntpair, const int* __restrict__ lvl_idx,
    const int* __restrict__ op_ids, const int* __restrict__ lch,
    const int* __restrict__ rch, const int* __restrict__ tch,
    bf16_t* __restrict__ ne2, const bf16_t* __restrict__ opb,
    const void* __restrict__ ct, const bf16_t* __restrict__ ctb,
    const int* __restrict__ cid, const int* __restrict__ inv,
    const int* __restrict__ flagp,
    const bf16_t* __restrict__ W1tp, const void* __restrict__ b1t,
    const bf16_t* __restrict__ W2tp, const void* __restrict__ b2t,
    const bf16_t* __restrict__ W1bp, const void* __restrict__ b1b,
    const bf16_t* __restrict__ W2bp, const void* __restrict__ b2b,
    const void* __restrict__ gma, const void* __restrict__ bta,
    int slotBase, void* __restrict__ out)
{
    __shared__ __align__(1024) char smem[69632];

    const int tid = threadIdx.x;
    const int w = tid >> 6, lane = tid & 63, cc = lane & 15, qq = lane >> 4;
    const int gx = (cc >> 1) & 3;   // chunk XOR for packed-weight / A reads
    const int e7 = cc & 7;          // chunk XOR for H
    const int cnt_t = cntpair[1], cnt_b = cntpair[0];
    const int blocks_t = (cnt_t + 31) >> 5;
    int tern, base, cnt, K1c;
    const int* list;
    const bf16_t *W1p, *W2p;
    const void *b1, *b2;
    if ((int)blockIdx.x < blocks_t) {
        tern = 1; list = list_t; base = blockIdx.x * 32; cnt = cnt_t;
        W1p = W1tp; b1 = b1t; W2p = W2tp; b2 = b2t; K1c = 32;
    } else {
        tern = 0; list = list_b; base = (blockIdx.x - blocks_t) * 32; cnt = cnt_b;
        if (base >= cnt) return;
        W1p = W1bp; b1 = b1b; W2p = W2bp; b2 = b2b; K1c = 24;
    }
    const int act = min(32, cnt - base);
    const int isbf = *flagp;

    // ---- per-thread row identity shared by A-staging and residual:
    //      row ms = tid>>3, 4-short col group g4 = tid&7
    const int ms = tid >> 3, g4 = tid & 7;
    const int lr = list[base + min(ms, act - 1)];
    const int node = lvl_idx[lr];
    const int c0 = lch[node], c1 = rch[node];
    const int c2 = tern ? tch[node] : c0;
    int sInv[3] = {inv[c0], inv[c1], inv[c2]};
    int sCid[3];
    sCid[0] = sInv[0] < 0 ? cid[c0] : 0;
    sCid[1] = sInv[1] < 0 ? cid[c1] : 0;
    sCid[2] = sInv[2] < 0 ? cid[c2] : 0;
    const bf16_t* pp0 = opb + (size_t)op_ids[node] * 256;
    const bf16_t* pp1 = sInv[0] >= 0 ? ne2 + (size_t)sInv[0] * 256 : ctb + (size_t)sCid[0] * 256;
    const bf16_t* pp2 = sInv[1] >= 0 ? ne2 + (size_t)sInv[1] * 256 : ctb + (size_t)sCid[1] * 256;
    const bf16_t* pp3 = sInv[2] >= 0 ? ne2 + (size_t)sInv[2] * 256 : ctb + (size_t)sCid[2] * 256;

    const f32x4 zf = {0.f, 0.f, 0.f, 0.f};
    f32x4 acc1[2][8];
    for (int m = 0; m < 2; m++) for (int j = 0; j < 8; j++) acc1[m][j] = zf;

    // ---------- GEMM1 (swapped operands): lane holds H[m*16+cc][(w+4j)*16+qq*4+r]
    for (int kc = 0; kc < K1c; kc++) {
        __syncthreads();            // previous chunk's reads done; slab free
        { // B1 slab: 32KB = 2048 x 16B, 8 per thread, load -> immediate ds_write
            const unsigned short* wsrc = (const unsigned short*)W1p + (size_t)kc * 16384;
            #pragma unroll
            for (int i = 0; i < 8; i++) {
                int idx = i * 256 + tid;
                u16x8 v = *(const u16x8*)(wsrc + idx * 8);
                *(u16x8*)(smem + idx * 16) = v;
            }
            // A chunk: thread (ms, g4) stages 4 shorts of concat(op,le,re[,te])
            int colg = kc * 32 + g4 * 4;
            int piece = colg >> 8, po = colg & 255;
            const bf16_t* s = pp0;
            s = piece == 1 ? pp1 : s;
            s = piece == 2 ? pp2 : s;
            s = piece == 3 ? pp3 : s;
            u16x4 va = *(const u16x4*)(s + po);
            int p = (g4 >> 1) ^ ((ms >> 1) & 3);     // dest chunk swizzle
            *(u16x4*)(smem + 65536 + ms * 64 + p * 16 + (g4 & 1) * 8) = va;
        }
        __syncthreads();            // slab ready
        const bf16_t* as = (const bf16_t*)(smem + 65536);
        const bf16_t* bs = (const bf16_t*)smem;
        bf16x8 af[2];
        for (int m = 0; m < 2; m++)
            af[m] = *(const bf16x8*)(as + (m * 16 + cc) * 32 + ((qq ^ gx) << 3));
        for (int j = 0; j < 8; j++) {
            bf16x8 bv = *(const bf16x8*)(bs + ((w + 4 * j) * 16 + cc) * 32 + ((qq ^ gx) << 3));
            for (int m = 0; m < 2; m++)
                acc1[m][j] = __builtin_amdgcn_mfma_f32_16x16x32_bf16(bv, af[m], acc1[m][j], 0, 0, 0);
        }
    }

    // ---------- bias + exact GELU -> H in LDS [32][512] bf16, chunk-swizzled
    // (H region disjoint from B1/A; no barrier needed before writing it)
    {
        char* Hb = smem + 32768;
        for (int m = 0; m < 2; m++) {
            int row = m * 16 + cc;
            for (int j = 0; j < 8; j++) {
                bf16x4 hv;
                for (int r = 0; r < 4; r++) {
                    float v = acc1[m][j][r] + ldparam(b1, (w + 4 * j) * 16 + qq * 4 + r, isbf);
                    hv[r] = (bf16_t)(0.5f * v * (1.0f + erff(v * 0.70710678118654752f)));
                }
                int c16 = ((w + 4 * j) << 1) + (qq >> 1);
                *(bf16x4*)(Hb + (row << 10) + ((c16 ^ e7) << 4) + ((qq & 1) << 3)) = hv;
            }
        }
    }

    // ---------- GEMM2: [32 x 512] @ [512 x 256]
    f32x4 acc2[2][4];
    for (int m = 0; m < 2; m++) for (int j = 0; j < 4; j++) acc2[m][j] = zf;
    for (int kc = 0; kc < 16; kc++) {
        __syncthreads();            // covers: H writes visible, B1/B2 reads done
        { // B2 slab: 16KB = 1024 x 16B, 4 per thread
            const unsigned short* wsrc = (const unsigned short*)W2p + (size_t)kc * 8192;
            #pragma unroll
            for (int i = 0; i < 4; i++) {
                int idx = i * 256 + tid;
                u16x8 v = *(const u16x8*)(wsrc + idx * 8);
                *(u16x8*)(smem + idx * 16) = v;
            }
        }
        __syncthreads();            // slab ready
        const char* Hb = smem + 32768;
        const bf16_t* bs = (const bf16_t*)smem;
        bf16x8 af[2];
        for (int m = 0; m < 2; m++)
            af[m] = *(const bf16x8*)(Hb + ((m * 16 + cc) << 10) + ((((kc << 2) + qq) ^ e7) << 4));
        for (int j = 0; j < 4; j++) {
            bf16x8 bv = *(const bf16x8*)(bs + ((w + 4 * j) * 16 + cc) * 32 + ((qq ^ gx) << 3));
            for (int m = 0; m < 2; m++)
                acc2[m][j] = __builtin_amdgcn_mfma_f32_16x16x32_bf16(af[m], bv, acc2[m][j], 0, 0, 0);
        }
    }
    __syncthreads();                // last H reads done; H region reusable

    // ---------- residual gather -> R float[32][256] (overlays H), col rotated by row*4
    {
        float* Rf = (float*)(smem + 32768);
        int colb = g4 * 32;
        for (int i = 0; i < 4; i++) {
            int q = colb + i * 8;
            float lv[8], rv[8], tv[8];
            load8f(ne2, ct, isbf, sInv[0], sCid[0], q, lv);
            load8f(ne2, ct, isbf, sInv[1], sCid[1], q, rv);
            if (tern) load8f(ne2, ct, isbf, sInv[2], sCid[2], q, tv);
            f32x4 s0, s1;
            if (tern) {
                for (int z = 0; z < 4; z++) {
                    s0[z] = (lv[z] + rv[z] + tv[z]) * (1.0f / 3.0f);
                    s1[z] = (lv[z + 4] + rv[z + 4] + tv[z + 4]) * (1.0f / 3.0f);
                }
            } else {
                for (int z = 0; z < 4; z++) {
                    s0[z] = lv[z] + rv[z];
                    s1[z] = lv[z + 4] + rv[z + 4];
                }
            }
            *(f32x4*)(Rf + ms * 256 + ((q + ms * 4) & 255)) = s0;
            *(f32x4*)(Rf + ms * 256 + ((q + 4 + ms * 4) & 255)) = s1;
        }
    }
    __syncthreads();

    // ---------- x = gemm2 + b2 + R ; LayerNorm over 256 cols per row
    float* partS = (float*)(smem + 67584); // [4][32]
    float* partQ = partS + 128;            // [4][32]
    float* muA   = partQ + 128;            // [32]
    float* rsA   = muA + 32;               // [32]
    const float* Rf = (const float*)(smem + 32768);

    float b2f[4], gf[4], btf[4];
    for (int j = 0; j < 4; j++) {
        int col = (w + 4 * j) * 16 + cc;
        b2f[j] = ldparam(b2, col, isbf);
        gf[j] = ldparam(gma, col, isbf);
        btf[j] = ldparam(bta, col, isbf);
    }

    for (int m = 0; m < 2; m++) for (int r = 0; r < 4; r++) {
        int row = m * 16 + qq * 4 + r;
        float ps = 0.f, pq = 0.f;
        for (int j = 0; j < 4; j++) {
            int col = (w + 4 * j) * 16 + cc;
            float x = acc2[m][j][r] + b2f[j] + Rf[(row << 8) + ((col + row * 4) & 255)];
            acc2[m][j][r] = x;
            ps += x; pq += x * x;
        }
        for (int d = 1; d < 16; d <<= 1) {
            ps += __shfl_xor(ps, d, 64);
            pq += __shfl_xor(pq, d, 64);
        }
        if (cc == 0) { partS[w * 32 + row] = ps; partQ[w * 32 + row] = pq; }
    }
    __syncthreads();
    if (tid < 32) {
        float s  = partS[tid] + partS[32 + tid] + partS[64 + tid] + partS[96 + tid];
        float sq = partQ[tid] + partQ[32 + tid] + partQ[64 + tid] + partQ[96 + tid];
        float mu = s * (1.0f / 256.0f);
        float var = sq * (1.0f / 256.0f) - mu * mu;
        muA[tid] = mu;
        rsA[tid] = rsqrtf(fmaxf(var, 0.0f) + 1e-5f);
    }
    __syncthreads();

    for (int m = 0; m < 2; m++) for (int r = 0; r < 4; r++) {
        int row = m * 16 + qq * 4 + r;
        if (row >= act) continue;
        float mu = muA[row], rs = rsA[row];
        int lr2 = list[base + row];
        for (int j = 0; j < 4; j++) {
            int col = (w + 4 * j) * 16 + cc;
            float y = (acc2[m][j][r] - mu) * rs * gf[j] + btf[j];
            if (out) {
                if (isbf) ((bf16_t*)out)[(size_t)lr2 * 256 + col] = (bf16_t)y;
                else      ((float*)out)[(size_t)lr2 * 256 + col] = y;
            } else {
                ne2[(size_t)(slotBase + lr2) * 256 + col] = (bf16_t)y;
            }
        }
    }
}

extern "C" void kernel_launch(void* const* d_in, const int* in_sizes, int n_in,
                              void* d_out, int out_size, void* d_ws, size_t ws_size,
                              hipStream_t stream) {
    const int* cid    = (const int*)d_in[0];
    const int* opids  = (const int*)d_in[1];
    const int* lch    = (const int*)d_in[2];
    const int* rch    = (const int*)d_in[3];
    const int* tch    = (const int*)d_in[4];
    const int* lvl2   = (const int*)d_in[5];
    const int* lvl1   = (const int*)d_in[6];
    const int* lvl0   = (const int*)d_in[7];
    const void* comp_table = d_in[8];
    const void* op_table   = d_in[9];
    const void* W1b = d_in[10];
    const void* b1b = d_in[11];
    const void* W2b = d_in[12];
    const void* b2b = d_in[13];
    const void* W1t = d_in[14];
    const void* b1t = d_in[15];
    const void* W2t = d_in[16];
    const void* b2t = d_in[17];
    const void* gma = d_in[18];
    const void* bta = d_in[19];

    char* wsp = (char*)d_ws;
    bf16_t* ne2  = (bf16_t*)wsp;                 size_t off = 12582912; // 24576*256*2
    bf16_t* opb  = (bf16_t*)(wsp + off);         off += 8192;           // 16*256*2
    bf16_t* ctb  = (bf16_t*)(wsp + off);         off += 1024000;        // 2000*256*2
    bf16_t* W1bp = (bf16_t*)(wsp + off);         off += 786432;         // 768*512*2
    bf16_t* W1tp = (bf16_t*)(wsp + off);         off += 1048576;        // 1024*512*2
    bf16_t* W2bp = (bf16_t*)(wsp + off);         off += 262144;         // 512*256*2
    bf16_t* W2tp = (bf16_t*)(wsp + off);         off += 262144;
    int* inv   = (int*)(wsp + off);              off += 262144;         // 65536*4
    int* lists = (int*)(wsp + off);              off += 229376;         // 57344*4
    int* cnts  = (int*)(wsp + off);              off += 64;             // total ~15.7 MiB
    int* flag  = cnts + 8;

    hipMemsetAsync(cnts, 0, 64, stream);
    hipMemsetAsync(inv, 0xFF, 262144, stream);
    detect_dtype<<<1, 64, 0, stream>>>((const unsigned short*)comp_table, flag);
    scan_rows<<<112, 256, 0, stream>>>(lvl2, lvl1, lvl0, tch, lists, cnts, inv);
    prep<<<6624, 256, 0, stream>>>(op_table, opb, comp_table, ctb,
                                   W1b, W1bp, W1t, W1tp, W2b, W2bp, W2t, W2tp, flag);

    // level 2: lists t @0 / b @16384, cnts slot 0 -> slots base 0
    fused_level<<<513, 256, 0, stream>>>(lists + 0, lists + 16384, cnts + 0, lvl2,
        opids, lch, rch, tch, ne2, opb, comp_table, ctb, cid, inv, flag,
        W1tp, b1t, W2tp, b2t, W1bp, b1b, W2bp, b2b, gma, bta, 0, nullptr);
    // level 1: lists t @32768 / b @40960, cnts slot 1 -> slots base 16384
    fused_level<<<257, 256, 0, stream>>>(lists + 32768, lists + 40960, cnts + 2, lvl1,
        opids, lch, rch, tch, ne2, opb, comp_table, ctb, cid, inv, flag,
        W1tp, b1t, W2tp, b2t, W1bp, b1b, W2bp, b2b, gma, bta, 16384, nullptr);
    // level 0: lists t @49152 / b @53248, cnts slot 2 -> d_out
    fused_level<<<129, 256, 0, stream>>>(lists + 49152, lists + 53248, cnts + 4, lvl0,
        opids, lch, rch, tch, ne2, opb, comp_table, ctb, cid, inv, flag,
        W1tp, b1t, W2tp, b2t, W1bp, b1b, W2bp, b2b, gma, bta, 0, d_out);
}

// Round 7
// 279.880 us; speedup vs baseline: 2.1144x; 1.7200x over previous
//
#include <hip/hip_runtime.h>

typedef __bf16 bf16_t;
typedef __attribute__((ext_vector_type(8))) __bf16 bf16x8;
typedef __attribute__((ext_vector_type(4))) float f32x4;
typedef __attribute__((ext_vector_type(8))) unsigned short u16x8;
typedef __attribute__((ext_vector_type(4))) unsigned short u16x4;

#define LBS 40    // B-slab / A-chunk LDS row stride in shorts (16B aligned)
#define LHS 520   // H LDS row stride in shorts (16B aligned)

// ---------------- dtype detect: 1 = bf16 inputs, 0 = fp32 inputs.
__global__ void detect_dtype(const unsigned short* __restrict__ ct, int* __restrict__ flag) {
    if (threadIdx.x == 0 && blockIdx.x == 0) {
        int ok = 1;
        for (int i = 0; i < 16; i++) {
            int e = (ct[256 + i] >> 7) & 0xFF;
            ok &= (e >= 80 && e <= 126) ? 1 : 0;
        }
        *flag = ok;
    }
}

// ---------------- merged prep: conv_op + 4x pack_w + scan_rows in one dispatch
// blocks [0,16): op_table -> bf16
// blocks [16,1552): pack W1b   [16,3600): W1t   [3600,4112): W2b   [4112,4624): W2t
//   pack: [K][N] -> [K/32][N][32] bf16 (identical math to R0's pack_w, NO swizzle)
// blocks [4624,4736): scan_rows (identical math to R0's scan_rows)
__global__ void prep(const void* __restrict__ op_table, bf16_t* __restrict__ opb,
                     const void* __restrict__ W1b, bf16_t* __restrict__ W1bp,
                     const void* __restrict__ W1t, bf16_t* __restrict__ W1tp,
                     const void* __restrict__ W2b, bf16_t* __restrict__ W2bp,
                     const void* __restrict__ W2t, bf16_t* __restrict__ W2tp,
                     const int* __restrict__ flagp,
                     const int* __restrict__ lvl2, const int* __restrict__ lvl1,
                     const int* __restrict__ lvl0, const int* __restrict__ third,
                     int* __restrict__ lists, int* __restrict__ cnts,
                     int* __restrict__ inv) {
    int b = blockIdx.x, tid = threadIdx.x;
    if (b >= 4624) {
        // ---- scan: wave-aggregated partition (1 atomic per wave per bucket)
        int r = (b - 4624) * 256 + tid;   // covers exactly 28672
        int slot, lr, base_t, base_b;
        const int* lvl;
        if (r < 16384)      { slot = 0; lr = r;         lvl = lvl2; base_t = 0;     base_b = 16384; }
        else if (r < 24576) { slot = 1; lr = r - 16384; lvl = lvl1; base_t = 32768; base_b = 40960; }
        else                { slot = 2; lr = r - 24576; lvl = lvl0; base_t = 49152; base_b = 53248; }
        int node = lvl[lr];
        int tern = third[node] >= 0 ? 1 : 0;
        if (slot == 0)      inv[node] = lr;          // lvl2 outputs -> slots [0,16384)
        else if (slot == 1) inv[node] = 16384 + lr;  // lvl1 outputs -> slots [16384,24576)

        unsigned long long bt = __ballot(tern);
        unsigned long long bb = __ballot(!tern);
        int lane = tid & 63;
        unsigned long long ltm = (1ull << lane) - 1ull;
        int post = __popcll(bt & ltm), posb = __popcll(bb & ltm);
        int baseT = 0, baseB = 0;
        if (lane == 0) {
            baseT = atomicAdd(&cnts[slot * 2 + 1], __popcll(bt));
            baseB = atomicAdd(&cnts[slot * 2 + 0], __popcll(bb));
        }
        baseT = __shfl(baseT, 0, 64);
        baseB = __shfl(baseB, 0, 64);
        lists[tern ? (base_t + baseT + post) : (base_b + baseB + posb)] = lr;
        return;
    }
    int isbf = *flagp;
    if (b < 16) {
        int i = b * 256 + tid;
        opb[i] = isbf ? ((const bf16_t*)op_table)[i] : (bf16_t)((const float*)op_table)[i];
        return;
    }
    const void* src; bf16_t* dst; int e0, Nmask, Nshift;
    if (b < 1552)      { src = W1b; dst = W1bp; e0 = (b - 16) * 256;   Nmask = 511; Nshift = 9; }
    else if (b < 3600) { src = W1t; dst = W1tp; e0 = (b - 1552) * 256; Nmask = 511; Nshift = 9; }
    else if (b < 4112) { src = W2b; dst = W2bp; e0 = (b - 3600) * 256; Nmask = 255; Nshift = 8; }
    else               { src = W2t; dst = W2tp; e0 = (b - 4112) * 256; Nmask = 255; Nshift = 8; }
    int e = e0 + tid;
    bf16_t v = isbf ? ((const bf16_t*)src)[e] : (bf16_t)((const float*)src)[e];
    int n = e & Nmask, k = e >> Nshift;
    dst[(size_t)((((k >> 5) << Nshift) + n) * 32 + (k & 31))] = v;
}

__device__ __forceinline__ void load8f(const bf16_t* ne2, const void* ct, int isbf,
                                       int invn, int cidn, int q, float* o) {
    if (invn >= 0) {
        bf16x8 v = *(const bf16x8*)(ne2 + (size_t)invn * 256 + q);
        for (int z = 0; z < 8; z++) o[z] = (float)v[z];
    } else if (isbf) {
        bf16x8 v = *(const bf16x8*)((const bf16_t*)ct + (size_t)cidn * 256 + q);
        for (int z = 0; z < 8; z++) o[z] = (float)v[z];
    } else {
        const float* fp = (const float*)ct + (size_t)cidn * 256 + q;
        f32x4 a = *(const f32x4*)fp, b = *(const f32x4*)(fp + 4);
        for (int z = 0; z < 4; z++) { o[z] = a[z]; o[z + 4] = b[z]; }
    }
}

__device__ __forceinline__ float ldparam(const void* p, int i, int isbf) {
    return isbf ? (float)((const bf16_t*)p)[i] : ((const float*)p)[i];
}

// ---------------- fused level kernel (merged tern+bin): blocks [0,blocks_t) ternary, rest binary
// VERBATIM from the verified 288.6us baseline (sane counters: WRITE 8MB, 71us/dispatch).
__global__ __launch_bounds__(256, 2) void fused_level(
    const int* __restrict__ list_t, const int* __restrict__ list_b,
    const int* __restrict__ cntpair, const int* __restrict__ lvl_idx,
    const int* __restrict__ op_ids, const int* __restrict__ lch,
    const int* __restrict__ rch, const int* __restrict__ tch,
    bf16_t* __restrict__ ne2, const bf16_t* __restrict__ opb,
    const void* __restrict__ ct, const int* __restrict__ cid,
    const int* __restrict__ inv, const int* __restrict__ flagp,
    const bf16_t* __restrict__ W1tp, const void* __restrict__ b1t,
    const bf16_t* __restrict__ W2tp, const void* __restrict__ b2t,
    const bf16_t* __restrict__ W1bp, const void* __restrict__ b1b,
    const bf16_t* __restrict__ W2bp, const void* __restrict__ b2b,
    const void* __restrict__ gma, const void* __restrict__ bta,
    int slotBase, void* __restrict__ out)
{
    __shared__ __align__(16) unsigned short reg1[20480]; // B1 slab [512][40] | H [32][520] | R float[32][260]
    __shared__ __align__(16) unsigned short regA[1280];  // A chunk [32][40]  | LN partials
    __shared__ __align__(16) unsigned short reg2[10240]; // B2 slab [256][40]

    const int tid = threadIdx.x;
    const int w = tid >> 6, lane = tid & 63, cc = lane & 15, qq = lane >> 4;
    const int cnt_t = cntpair[1], cnt_b = cntpair[0];
    const int blocks_t = (cnt_t + 31) >> 5;
    int tern, base, cnt, K1c;
    const int* list;
    const bf16_t *W1p, *W2p;
    const void *b1, *b2;
    if ((int)blockIdx.x < blocks_t) {
        tern = 1; list = list_t; base = blockIdx.x * 32; cnt = cnt_t;
        W1p = W1tp; b1 = b1t; W2p = W2tp; b2 = b2t; K1c = 32;
    } else {
        tern = 0; list = list_b; base = (blockIdx.x - blocks_t) * 32; cnt = cnt_b;
        if (base >= cnt) return;
        W1p = W1bp; b1 = b1b; W2p = W2bp; b2 = b2b; K1c = 24;
    }
    const int act = min(32, cnt - base);
    const int isbf = *flagp;

    // staging identity: thread covers row ms, col-group gs
    const int ms = tid >> 3, gs = tid & 7;
    const int rowS = list[base + min(ms, act - 1)];
    const int nodeS = lvl_idx[rowS];
    const int opS = op_ids[nodeS];
    const int lS = lch[nodeS], rS = rch[nodeS];
    const int tS = tern ? tch[nodeS] : lS;
    int sInv[3], sCid[3];
    {
        int sn[3] = {lS, rS, tS};
        for (int s = 0; s < 3; s++) {
            sInv[s] = inv[sn[s]];
            sCid[s] = sInv[s] < 0 ? cid[sn[s]] : 0;
        }
    }

    // per-lane bias / gamma / beta (cols owned by this lane)
    float b1f[8];
    for (int j = 0; j < 8; j++) b1f[j] = ldparam(b1, (w + 4 * j) * 16 + cc, isbf);
    float b2f[4], gf[4], btf[4];
    for (int j = 0; j < 4; j++) {
        int col = (w + 4 * j) * 16 + cc;
        b2f[j] = ldparam(b2, col, isbf);
        gf[j] = ldparam(gma, col, isbf);
        btf[j] = ldparam(bta, col, isbf);
    }

    const f32x4 zf = {0.f, 0.f, 0.f, 0.f};
    f32x4 acc1[2][8];
    for (int m = 0; m < 2; m++) for (int j = 0; j < 8; j++) acc1[m][j] = zf;

    // ---------- GEMM1: [32 x K1] @ [K1 x 512]
    for (int kc = 0; kc < K1c; kc++) {
        __syncthreads();
        { // A chunk gather: 32 rows x 32 cols of concat(op,le,re[,te])
            int colg = kc * 32 + gs * 4;
            int piece = colg >> 8, po = colg & 255;
            u16x4 hv;
            if (piece == 0) {
                hv = *(const u16x4*)((const unsigned short*)opb + opS * 256 + po);
            } else {
                int s = piece - 1;
                if (sInv[s] >= 0) {
                    hv = *(const u16x4*)((const unsigned short*)ne2 + (size_t)sInv[s] * 256 + po);
                } else if (isbf) {
                    hv = *(const u16x4*)((const unsigned short*)ct + (size_t)sCid[s] * 256 + po);
                } else {
                    f32x4 fv = *(const f32x4*)((const float*)ct + (size_t)sCid[s] * 256 + po);
                    bf16_t tmp[4];
                    for (int z = 0; z < 4; z++) tmp[z] = (bf16_t)fv[z];
                    hv = *(u16x4*)tmp;
                }
            }
            *(u16x4*)(regA + ms * LBS + gs * 4) = hv;
        }
        // B slab: 512n x 32k shorts = 2048 16B chunks, 8 per thread
        for (int i = 0; i < 8; i++) {
            int idx = i * 256 + tid;
            int n = idx >> 2, g = idx & 3;
            u16x8 v = *(const u16x8*)((const unsigned short*)W1p + ((size_t)kc * 512 + n) * 32 + g * 8);
            *(u16x8*)(reg1 + n * LBS + g * 8) = v;
        }
        __syncthreads();
        bf16x8 af[2];
        for (int m = 0; m < 2; m++)
            af[m] = *(const bf16x8*)((const bf16_t*)regA + (m * 16 + cc) * LBS + qq * 8);
        for (int j = 0; j < 8; j++) {
            bf16x8 bfv = *(const bf16x8*)((const bf16_t*)reg1 + ((w + 4 * j) * 16 + cc) * LBS + qq * 8);
            for (int m = 0; m < 2; m++)
                acc1[m][j] = __builtin_amdgcn_mfma_f32_16x16x32_bf16(af[m], bfv, acc1[m][j], 0, 0, 0);
        }
    }
    __syncthreads();

    // ---------- bias + exact GELU -> H in LDS [32][512] (stride 520)
    {
        bf16_t* Hl = (bf16_t*)reg1;
        for (int m = 0; m < 2; m++) for (int j = 0; j < 8; j++) {
            int col = (w + 4 * j) * 16 + cc;
            for (int r = 0; r < 4; r++) {
                float v = acc1[m][j][r] + b1f[j];
                float h = 0.5f * v * (1.0f + erff(v * 0.70710678118654752f));
                Hl[(m * 16 + qq * 4 + r) * LHS + col] = (bf16_t)h;
            }
        }
    }
    __syncthreads();

    // ---------- GEMM2: [32 x 512] @ [512 x 256]
    f32x4 acc2[2][4];
    for (int m = 0; m < 2; m++) for (int j = 0; j < 4; j++) acc2[m][j] = zf;
    for (int kc = 0; kc < 16; kc++) {
        if (kc) __syncthreads();
        for (int i = 0; i < 4; i++) {
            int idx = i * 256 + tid;
            int n = idx >> 2, g = idx & 3;
            u16x8 v = *(const u16x8*)((const unsigned short*)W2p + ((size_t)kc * 256 + n) * 32 + g * 8);
            *(u16x8*)(reg2 + n * LBS + g * 8) = v;
        }
        __syncthreads();
        bf16x8 af[2];
        for (int m = 0; m < 2; m++)
            af[m] = *(const bf16x8*)((const bf16_t*)reg1 + (m * 16 + cc) * LHS + kc * 32 + qq * 8);
        for (int j = 0; j < 4; j++) {
            bf16x8 bfv = *(const bf16x8*)((const bf16_t*)reg2 + ((w + 4 * j) * 16 + cc) * LBS + qq * 8);
            for (int m = 0; m < 2; m++)
                acc2[m][j] = __builtin_amdgcn_mfma_f32_16x16x32_bf16(af[m], bfv, acc2[m][j], 0, 0, 0);
        }
    }
    __syncthreads();

    // ---------- residual gather -> reg1 as float[32][260]
    {
        float* Rf = (float*)reg1;
        int colb = gs * 32;
        for (int i = 0; i < 4; i++) {
            int q = colb + i * 8;
            float lv[8], rv[8], tv[8];
            load8f(ne2, ct, isbf, sInv[0], sCid[0], q, lv);
            load8f(ne2, ct, isbf, sInv[1], sCid[1], q, rv);
            if (tern) load8f(ne2, ct, isbf, sInv[2], sCid[2], q, tv);
            f32x4 s0, s1;
            if (tern) {
                for (int z = 0; z < 4; z++) {
                    s0[z] = (lv[z] + rv[z] + tv[z]) * (1.0f / 3.0f);
                    s1[z] = (lv[z + 4] + rv[z + 4] + tv[z + 4]) * (1.0f / 3.0f);
                }
            } else {
                for (int z = 0; z < 4; z++) {
                    s0[z] = lv[z] + rv[z];
                    s1[z] = lv[z + 4] + rv[z + 4];
                }
            }
            *(f32x4*)(Rf + ms * 260 + q) = s0;
            *(f32x4*)(Rf + ms * 260 + q + 4) = s1;
        }
    }
    __syncthreads();

    // ---------- x = gemm2 + b2 + R ; LayerNorm over 256 cols per row
    float* partS = (float*)regA;      // [4][32]
    float* partQ = partS + 128;       // [4][32]
    float* muA   = partQ + 128;       // [32]
    float* rsA   = muA + 32;          // [32]
    const float* Rf = (const float*)reg1;

    for (int m = 0; m < 2; m++) for (int r = 0; r < 4; r++) {
        int row = m * 16 + qq * 4 + r;
        float ps = 0.f, pq = 0.f;
        for (int j = 0; j < 4; j++) {
            int col = (w + 4 * j) * 16 + cc;
            float x = acc2[m][j][r] + b2f[j] + Rf[row * 260 + col];
            acc2[m][j][r] = x;
            ps += x; pq += x * x;
        }
        for (int d = 1; d < 16; d <<= 1) {
            ps += __shfl_xor(ps, d, 64);
            pq += __shfl_xor(pq, d, 64);
        }
        if (cc == 0) { partS[w * 32 + row] = ps; partQ[w * 32 + row] = pq; }
    }
    __syncthreads();
    if (tid < 32) {
        float s  = partS[tid] + partS[32 + tid] + partS[64 + tid] + partS[96 + tid];
        float sq = partQ[tid] + partQ[32 + tid] + partQ[64 + tid] + partQ[96 + tid];
        float mu = s * (1.0f / 256.0f);
        float var = sq * (1.0f / 256.0f) - mu * mu;
        muA[tid] = mu;
        rsA[tid] = rsqrtf(fmaxf(var, 0.0f) + 1e-5f);
    }
    __syncthreads();

    for (int m = 0; m < 2; m++) for (int r = 0; r < 4; r++) {
        int row = m * 16 + qq * 4 + r;
        if (row >= act) continue;
        float mu = muA[row], rs = rsA[row];
        int lr2 = list[base + row];
        for (int j = 0; j < 4; j++) {
            int col = (w + 4 * j) * 16 + cc;
            float y = (acc2[m][j][r] - mu) * rs * gf[j] + btf[j];
            if (out) {
                if (isbf) ((bf16_t*)out)[(size_t)lr2 * 256 + col] = (bf16_t)y;
                else      ((float*)out)[(size_t)lr2 * 256 + col] = y;
            } else {
                ne2[(size_t)(slotBase + lr2) * 256 + col] = (bf16_t)y;
            }
        }
    }
}

extern "C" void kernel_launch(void* const* d_in, const int* in_sizes, int n_in,
                              void* d_out, int out_size, void* d_ws, size_t ws_size,
                              hipStream_t stream) {
    const int* cid    = (const int*)d_in[0];
    const int* opids  = (const int*)d_in[1];
    const int* lch    = (const int*)d_in[2];
    const int* rch    = (const int*)d_in[3];
    const int* tch    = (const int*)d_in[4];
    const int* lvl2   = (const int*)d_in[5];
    const int* lvl1   = (const int*)d_in[6];
    const int* lvl0   = (const int*)d_in[7];
    const void* comp_table = d_in[8];
    const void* op_table   = d_in[9];
    const void* W1b = d_in[10];
    const void* b1b = d_in[11];
    const void* W2b = d_in[12];
    const void* b2b = d_in[13];
    const void* W1t = d_in[14];
    const void* b1t = d_in[15];
    const void* W2t = d_in[16];
    const void* b2t = d_in[17];
    const void* gma = d_in[18];
    const void* bta = d_in[19];

    char* wsp = (char*)d_ws;
    bf16_t* ne2  = (bf16_t*)wsp;                 size_t off = 12582912; // 24576*256*2
    bf16_t* opb  = (bf16_t*)(wsp + off);         off += 8192;           // 16*256*2
    bf16_t* W1bp = (bf16_t*)(wsp + off);         off += 786432;         // 768*512*2
    bf16_t* W1tp = (bf16_t*)(wsp + off);         off += 1048576;        // 1024*512*2
    bf16_t* W2bp = (bf16_t*)(wsp + off);         off += 262144;         // 512*256*2
    bf16_t* W2tp = (bf16_t*)(wsp + off);         off += 262144;
    int* inv   = (int*)(wsp + off);              off += 262144;         // 65536*4
    int* lists = (int*)(wsp + off);              off += 229376;         // 57344*4
    int* cnts  = (int*)(wsp + off);              off += 64;             // total ~15.4 MB
    int* flag  = cnts + 8;

    hipMemsetAsync(cnts, 0, 64, stream);
    hipMemsetAsync(inv, 0xFF, 262144, stream);
    detect_dtype<<<1, 64, 0, stream>>>((const unsigned short*)comp_table, flag);
    // one merged prep dispatch: conv_op + pack_w x4 + scan_rows
    prep<<<4736, 256, 0, stream>>>(op_table, opb,
                                   W1b, W1bp, W1t, W1tp, W2b, W2bp, W2t, W2tp, flag,
                                   lvl2, lvl1, lvl0, tch, lists, cnts, inv);

    // level 2: lists t @0 / b @16384, cnts slot 0 -> slots base 0
    fused_level<<<513, 256, 0, stream>>>(lists + 0, lists + 16384, cnts + 0, lvl2,
        opids, lch, rch, tch, ne2, opb, comp_table, cid, inv, flag,
        W1tp, b1t, W2tp, b2t, W1bp, b1b, W2bp, b2b, gma, bta, 0, nullptr);
    // level 1: lists t @32768 / b @40960, cnts slot 1 -> slots base 16384
    fused_level<<<257, 256, 0, stream>>>(lists + 32768, lists + 40960, cnts + 2, lvl1,
        opids, lch, rch, tch, ne2, opb, comp_table, cid, inv, flag,
        W1tp, b1t, W2tp, b2t, W1bp, b1b, W2bp, b2b, gma, bta, 16384, nullptr);
    // level 0: lists t @49152 / b @53248, cnts slot 2 -> d_out
    fused_level<<<129, 256, 0, stream>>>(lists + 49152, lists + 53248, cnts + 4, lvl0,
        opids, lch, rch, tch, ne2, opb, comp_table, cid, inv, flag,
        W1tp, b1t, W2tp, b2t, W1bp, b1b, W2bp, b2b, gma, bta, 0, d_out);
}

// Round 8
// 276.986 us; speedup vs baseline: 2.1365x; 1.0104x over previous
//
#include <hip/hip_runtime.h>

typedef __bf16 bf16_t;
typedef __attribute__((ext_vector_type(8))) __bf16 bf16x8;
typedef __attribute__((ext_vector_type(4))) __bf16 bf16x4;
typedef __attribute__((ext_vector_type(4))) float f32x4;
typedef __attribute__((ext_vector_type(8))) unsigned short u16x8;
typedef __attribute__((ext_vector_type(4))) unsigned short u16x4;

#define LBA 40    // A-chunk LDS row stride in shorts (16B aligned, unchanged from R7)

// ---------------- dtype detect: 1 = bf16 inputs, 0 = fp32 inputs.
__global__ void detect_dtype(const unsigned short* __restrict__ ct, int* __restrict__ flag) {
    if (threadIdx.x == 0 && blockIdx.x == 0) {
        int ok = 1;
        for (int i = 0; i < 16; i++) {
            int e = (ct[256 + i] >> 7) & 0xFF;
            ok &= (e >= 80 && e <= 126) ? 1 : 0;
        }
        *flag = ok;
    }
}

// ---------------- merged prep: conv_op + 4x pack_w + scan_rows in one dispatch
// blocks [0,16): op_table -> bf16
// blocks [16,1552): pack W1b   [16,3600): W1t   [3600,4112): W2b   [4112,4624): W2t
//   pack: [K][N] -> [K/32][N][32] bf16 (identical math to R0's pack_w, NO swizzle)
// blocks [4624,4736): scan_rows (identical math to R0's scan_rows)
__global__ void prep(const void* __restrict__ op_table, bf16_t* __restrict__ opb,
                     const void* __restrict__ W1b, bf16_t* __restrict__ W1bp,
                     const void* __restrict__ W1t, bf16_t* __restrict__ W1tp,
                     const void* __restrict__ W2b, bf16_t* __restrict__ W2bp,
                     const void* __restrict__ W2t, bf16_t* __restrict__ W2tp,
                     const int* __restrict__ flagp,
                     const int* __restrict__ lvl2, const int* __restrict__ lvl1,
                     const int* __restrict__ lvl0, const int* __restrict__ third,
                     int* __restrict__ lists, int* __restrict__ cnts,
                     int* __restrict__ inv) {
    int b = blockIdx.x, tid = threadIdx.x;
    if (b >= 4624) {
        // ---- scan: wave-aggregated partition (1 atomic per wave per bucket)
        int r = (b - 4624) * 256 + tid;   // covers exactly 28672
        int slot, lr, base_t, base_b;
        const int* lvl;
        if (r < 16384)      { slot = 0; lr = r;         lvl = lvl2; base_t = 0;     base_b = 16384; }
        else if (r < 24576) { slot = 1; lr = r - 16384; lvl = lvl1; base_t = 32768; base_b = 40960; }
        else                { slot = 2; lr = r - 24576; lvl = lvl0; base_t = 49152; base_b = 53248; }
        int node = lvl[lr];
        int tern = third[node] >= 0 ? 1 : 0;
        if (slot == 0)      inv[node] = lr;          // lvl2 outputs -> slots [0,16384)
        else if (slot == 1) inv[node] = 16384 + lr;  // lvl1 outputs -> slots [16384,24576)

        unsigned long long bt = __ballot(tern);
        unsigned long long bb = __ballot(!tern);
        int lane = tid & 63;
        unsigned long long ltm = (1ull << lane) - 1ull;
        int post = __popcll(bt & ltm), posb = __popcll(bb & ltm);
        int baseT = 0, baseB = 0;
        if (lane == 0) {
            baseT = atomicAdd(&cnts[slot * 2 + 1], __popcll(bt));
            baseB = atomicAdd(&cnts[slot * 2 + 0], __popcll(bb));
        }
        baseT = __shfl(baseT, 0, 64);
        baseB = __shfl(baseB, 0, 64);
        lists[tern ? (base_t + baseT + post) : (base_b + baseB + posb)] = lr;
        return;
    }
    int isbf = *flagp;
    if (b < 16) {
        int i = b * 256 + tid;
        opb[i] = isbf ? ((const bf16_t*)op_table)[i] : (bf16_t)((const float*)op_table)[i];
        return;
    }
    const void* src; bf16_t* dst; int e0, Nmask, Nshift;
    if (b < 1552)      { src = W1b; dst = W1bp; e0 = (b - 16) * 256;   Nmask = 511; Nshift = 9; }
    else if (b < 3600) { src = W1t; dst = W1tp; e0 = (b - 1552) * 256; Nmask = 511; Nshift = 9; }
    else if (b < 4112) { src = W2b; dst = W2bp; e0 = (b - 3600) * 256; Nmask = 255; Nshift = 8; }
    else               { src = W2t; dst = W2tp; e0 = (b - 4112) * 256; Nmask = 255; Nshift = 8; }
    int e = e0 + tid;
    bf16_t v = isbf ? ((const bf16_t*)src)[e] : (bf16_t)((const float*)src)[e];
    int n = e & Nmask, k = e >> Nshift;
    dst[(size_t)((((k >> 5) << Nshift) + n) * 32 + (k & 31))] = v;
}

__device__ __forceinline__ void load8f(const bf16_t* ne2, const void* ct, int isbf,
                                       int invn, int cidn, int q, float* o) {
    if (invn >= 0) {
        bf16x8 v = *(const bf16x8*)(ne2 + (size_t)invn * 256 + q);
        for (int z = 0; z < 8; z++) o[z] = (float)v[z];
    } else if (isbf) {
        bf16x8 v = *(const bf16x8*)((const bf16_t*)ct + (size_t)cidn * 256 + q);
        for (int z = 0; z < 8; z++) o[z] = (float)v[z];
    } else {
        const float* fp = (const float*)ct + (size_t)cidn * 256 + q;
        f32x4 a = *(const f32x4*)fp, b = *(const f32x4*)(fp + 4);
        for (int z = 0; z < 4; z++) { o[z] = a[z]; o[z + 4] = b[z]; }
    }
}

__device__ __forceinline__ float ldparam(const void* p, int i, int isbf) {
    return isbf ? (float)((const bf16_t*)p)[i] : ((const float*)p)[i];
}

// ---------------- fused level kernel (merged tern+bin): blocks [0,blocks_t) ternary, rest binary
// R7 skeleton (same barriers, same global access byte-for-byte, same register style) with:
//  - B1/B2 LDS stride 32 + 16B-chunk XOR swizzle (write g^((n>>1)&3), read qq^gx)
//  - GEMM1 operand-swapped -> lane owns 4 consecutive H cols -> bf16x4 H writes
//  - H [32][512] stride-512 with chunk XOR (c16 ^ (row&7)); GEMM2 reads with same XOR
//  - R float[32][256] (no pad; LN read is qq-broadcast, conflict-free)
//  - LDS 51712 B -> 3 blocks/CU via __launch_bounds__(256,3)
__global__ __launch_bounds__(256, 3) void fused_level(
    const int* __restrict__ list_t, const int* __restrict__ list_b,
    const int* __restrict__ cntpair, const int* __restrict__ lvl_idx,
    const int* __restrict__ op_ids, const int* __restrict__ lch,
    const int* __restrict__ rch, const int* __restrict__ tch,
    bf16_t* __restrict__ ne2, const bf16_t* __restrict__ opb,
    const void* __restrict__ ct, const int* __restrict__ cid,
    const int* __restrict__ inv, const int* __restrict__ flagp,
    const bf16_t* __restrict__ W1tp, const void* __restrict__ b1t,
    const bf16_t* __restrict__ W2tp, const void* __restrict__ b2t,
    const bf16_t* __restrict__ W1bp, const void* __restrict__ b1b,
    const bf16_t* __restrict__ W2bp, const void* __restrict__ b2b,
    const void* __restrict__ gma, const void* __restrict__ bta,
    int slotBase, void* __restrict__ out)
{
    __shared__ __align__(16) unsigned short reg1[16384]; // B1 [512][32] | H [32][512] swz | R float[32][256]
    __shared__ __align__(16) unsigned short regA[1280];  // A chunk [32][40] | LN partials
    __shared__ __align__(16) unsigned short reg2[8192];  // B2 [256][32]

    const int tid = threadIdx.x;
    const int w = tid >> 6, lane = tid & 63, cc = lane & 15, qq = lane >> 4;
    const int gx = (cc >> 1) & 3;   // B-slab read chunk XOR
    const int e7 = cc & 7;          // H chunk XOR (row&7 with row = m*16+cc)
    const int cnt_t = cntpair[1], cnt_b = cntpair[0];
    const int blocks_t = (cnt_t + 31) >> 5;
    int tern, base, cnt, K1c;
    const int* list;
    const bf16_t *W1p, *W2p;
    const void *b1, *b2;
    if ((int)blockIdx.x < blocks_t) {
        tern = 1; list = list_t; base = blockIdx.x * 32; cnt = cnt_t;
        W1p = W1tp; b1 = b1t; W2p = W2tp; b2 = b2t; K1c = 32;
    } else {
        tern = 0; list = list_b; base = (blockIdx.x - blocks_t) * 32; cnt = cnt_b;
        if (base >= cnt) return;
        W1p = W1bp; b1 = b1b; W2p = W2bp; b2 = b2b; K1c = 24;
    }
    const int act = min(32, cnt - base);
    const int isbf = *flagp;

    // staging identity: thread covers row ms, col-group gs
    const int ms = tid >> 3, gs = tid & 7;
    const int rowS = list[base + min(ms, act - 1)];
    const int nodeS = lvl_idx[rowS];
    const int opS = op_ids[nodeS];
    const int lS = lch[nodeS], rS = rch[nodeS];
    const int tS = tern ? tch[nodeS] : lS;
    int sInv[3], sCid[3];
    {
        int sn[3] = {lS, rS, tS};
        for (int s = 0; s < 3; s++) {
            sInv[s] = inv[sn[s]];
            sCid[s] = sInv[s] < 0 ? cid[sn[s]] : 0;
        }
    }

    // per-lane params for GEMM2 epilogue (cols owned by this lane)
    float b2f[4], gf[4], btf[4];
    for (int j = 0; j < 4; j++) {
        int col = (w + 4 * j) * 16 + cc;
        b2f[j] = ldparam(b2, col, isbf);
        gf[j] = ldparam(gma, col, isbf);
        btf[j] = ldparam(bta, col, isbf);
    }

    const f32x4 zf = {0.f, 0.f, 0.f, 0.f};
    f32x4 acc1[2][8];
    for (int m = 0; m < 2; m++) for (int j = 0; j < 8; j++) acc1[m][j] = zf;

    // ---------- GEMM1 (swapped): acc1[m][j] reg r = H[m*16+cc][(w+4j)*16+qq*4+r]
    for (int kc = 0; kc < K1c; kc++) {
        __syncthreads();
        { // A chunk gather: 32 rows x 32 cols of concat(op,le,re[,te])  [R7 verbatim]
            int colg = kc * 32 + gs * 4;
            int piece = colg >> 8, po = colg & 255;
            u16x4 hv;
            if (piece == 0) {
                hv = *(const u16x4*)((const unsigned short*)opb + opS * 256 + po);
            } else {
                int s = piece - 1;
                if (sInv[s] >= 0) {
                    hv = *(const u16x4*)((const unsigned short*)ne2 + (size_t)sInv[s] * 256 + po);
                } else if (isbf) {
                    hv = *(const u16x4*)((const unsigned short*)ct + (size_t)sCid[s] * 256 + po);
                } else {
                    f32x4 fv = *(const f32x4*)((const float*)ct + (size_t)sCid[s] * 256 + po);
                    bf16_t tmp[4];
                    for (int z = 0; z < 4; z++) tmp[z] = (bf16_t)fv[z];
                    hv = *(u16x4*)tmp;
                }
            }
            *(u16x4*)(regA + ms * LBA + gs * 4) = hv;
        }
        // B slab: 512n x 32k shorts, global read R7-verbatim; LDS dest chunk-XOR swizzled
        for (int i = 0; i < 8; i++) {
            int idx = i * 256 + tid;
            int n = idx >> 2, g = idx & 3;
            u16x8 v = *(const u16x8*)((const unsigned short*)W1p + ((size_t)kc * 512 + n) * 32 + g * 8);
            *(u16x8*)(reg1 + n * 32 + ((g ^ ((n >> 1) & 3)) << 3)) = v;
        }
        __syncthreads();
        bf16x8 af[2];
        for (int m = 0; m < 2; m++)
            af[m] = *(const bf16x8*)((const bf16_t*)regA + (m * 16 + cc) * LBA + qq * 8);
        for (int j = 0; j < 8; j++) {
            bf16x8 bfv = *(const bf16x8*)((const bf16_t*)reg1 + ((w + 4 * j) * 16 + cc) * 32 + ((qq ^ gx) << 3));
            for (int m = 0; m < 2; m++)
                acc1[m][j] = __builtin_amdgcn_mfma_f32_16x16x32_bf16(bfv, af[m], acc1[m][j], 0, 0, 0);
        }
    }
    __syncthreads();

    // ---------- bias + exact GELU -> H [32][512] stride-512, chunk-XOR, bf16x4 stores
    {
        for (int j = 0; j < 8; j++) {
            float b1q[4];
            for (int r = 0; r < 4; r++) b1q[r] = ldparam(b1, (w + 4 * j) * 16 + qq * 4 + r, isbf);
            int c16 = ((w + 4 * j) << 1) + (qq >> 1);
            for (int m = 0; m < 2; m++) {
                int row = m * 16 + cc;
                bf16x4 hv;
                for (int r = 0; r < 4; r++) {
                    float v = acc1[m][j][r] + b1q[r];
                    hv[r] = (bf16_t)(0.5f * v * (1.0f + erff(v * 0.70710678118654752f)));
                }
                *(bf16x4*)(reg1 + (row << 9) + ((c16 ^ e7) << 3) + ((qq & 1) << 2)) = hv;
            }
        }
    }
    __syncthreads();

    // ---------- GEMM2: [32 x 512] @ [512 x 256]
    f32x4 acc2[2][4];
    for (int m = 0; m < 2; m++) for (int j = 0; j < 4; j++) acc2[m][j] = zf;
    for (int kc = 0; kc < 16; kc++) {
        if (kc) __syncthreads();
        for (int i = 0; i < 4; i++) {
            int idx = i * 256 + tid;
            int n = idx >> 2, g = idx & 3;
            u16x8 v = *(const u16x8*)((const unsigned short*)W2p + ((size_t)kc * 256 + n) * 32 + g * 8);
            *(u16x8*)(reg2 + n * 32 + ((g ^ ((n >> 1) & 3)) << 3)) = v;
        }
        __syncthreads();
        bf16x8 af[2];
        for (int m = 0; m < 2; m++)
            af[m] = *(const bf16x8*)((const bf16_t*)reg1 + ((m * 16 + cc) << 9) + ((((kc << 2) + qq) ^ e7) << 3));
        for (int j = 0; j < 4; j++) {
            bf16x8 bfv = *(const bf16x8*)((const bf16_t*)reg2 + ((w + 4 * j) * 16 + cc) * 32 + ((qq ^ gx) << 3));
            for (int m = 0; m < 2; m++)
                acc2[m][j] = __builtin_amdgcn_mfma_f32_16x16x32_bf16(af[m], bfv, acc2[m][j], 0, 0, 0);
        }
    }
    __syncthreads();

    // ---------- residual gather -> reg1 as float[32][256]
    {
        float* Rf = (float*)reg1;
        int colb = gs * 32;
        for (int i = 0; i < 4; i++) {
            int q = colb + i * 8;
            float lv[8], rv[8], tv[8];
            load8f(ne2, ct, isbf, sInv[0], sCid[0], q, lv);
            load8f(ne2, ct, isbf, sInv[1], sCid[1], q, rv);
            if (tern) load8f(ne2, ct, isbf, sInv[2], sCid[2], q, tv);
            f32x4 s0, s1;
            if (tern) {
                for (int z = 0; z < 4; z++) {
                    s0[z] = (lv[z] + rv[z] + tv[z]) * (1.0f / 3.0f);
                    s1[z] = (lv[z + 4] + rv[z + 4] + tv[z + 4]) * (1.0f / 3.0f);
                }
            } else {
                for (int z = 0; z < 4; z++) {
                    s0[z] = lv[z] + rv[z];
                    s1[z] = lv[z + 4] + rv[z + 4];
                }
            }
            *(f32x4*)(Rf + ms * 256 + q) = s0;
            *(f32x4*)(Rf + ms * 256 + q + 4) = s1;
        }
    }
    __syncthreads();

    // ---------- x = gemm2 + b2 + R ; LayerNorm over 256 cols per row
    float* partS = (float*)regA;      // [4][32]
    float* partQ = partS + 128;       // [4][32]
    float* muA   = partQ + 128;       // [32]
    float* rsA   = muA + 32;          // [32]
    const float* Rf = (const float*)reg1;

    for (int m = 0; m < 2; m++) for (int r = 0; r < 4; r++) {
        int row = m * 16 + qq * 4 + r;
        float ps = 0.f, pq = 0.f;
        for (int j = 0; j < 4; j++) {
            int col = (w + 4 * j) * 16 + cc;
            float x = acc2[m][j][r] + b2f[j] + Rf[(row << 8) + col];
            acc2[m][j][r] = x;
            ps += x; pq += x * x;
        }
        for (int d = 1; d < 16; d <<= 1) {
            ps += __shfl_xor(ps, d, 64);
            pq += __shfl_xor(pq, d, 64);
        }
        if (cc == 0) { partS[w * 32 + row] = ps; partQ[w * 32 + row] = pq; }
    }
    __syncthreads();
    if (tid < 32) {
        float s  = partS[tid] + partS[32 + tid] + partS[64 + tid] + partS[96 + tid];
        float sq = partQ[tid] + partQ[32 + tid] + partQ[64 + tid] + partQ[96 + tid];
        float mu = s * (1.0f / 256.0f);
        float var = sq * (1.0f / 256.0f) - mu * mu;
        muA[tid] = mu;
        rsA[tid] = rsqrtf(fmaxf(var, 0.0f) + 1e-5f);
    }
    __syncthreads();

    for (int m = 0; m < 2; m++) for (int r = 0; r < 4; r++) {
        int row = m * 16 + qq * 4 + r;
        if (row >= act) continue;
        float mu = muA[row], rs = rsA[row];
        int lr2 = list[base + row];
        for (int j = 0; j < 4; j++) {
            int col = (w + 4 * j) * 16 + cc;
            float y = (acc2[m][j][r] - mu) * rs * gf[j] + btf[j];
            if (out) {
                if (isbf) ((bf16_t*)out)[(size_t)lr2 * 256 + col] = (bf16_t)y;
                else      ((float*)out)[(size_t)lr2 * 256 + col] = y;
            } else {
                ne2[(size_t)(slotBase + lr2) * 256 + col] = (bf16_t)y;
            }
        }
    }
}

extern "C" void kernel_launch(void* const* d_in, const int* in_sizes, int n_in,
                              void* d_out, int out_size, void* d_ws, size_t ws_size,
                              hipStream_t stream) {
    const int* cid    = (const int*)d_in[0];
    const int* opids  = (const int*)d_in[1];
    const int* lch    = (const int*)d_in[2];
    const int* rch    = (const int*)d_in[3];
    const int* tch    = (const int*)d_in[4];
    const int* lvl2   = (const int*)d_in[5];
    const int* lvl1   = (const int*)d_in[6];
    const int* lvl0   = (const int*)d_in[7];
    const void* comp_table = d_in[8];
    const void* op_table   = d_in[9];
    const void* W1b = d_in[10];
    const void* b1b = d_in[11];
    const void* W2b = d_in[12];
    const void* b2b = d_in[13];
    const void* W1t = d_in[14];
    const void* b1t = d_in[15];
    const void* W2t = d_in[16];
    const void* b2t = d_in[17];
    const void* gma = d_in[18];
    const void* bta = d_in[19];

    char* wsp = (char*)d_ws;
    bf16_t* ne2  = (bf16_t*)wsp;                 size_t off = 12582912; // 24576*256*2
    bf16_t* opb  = (bf16_t*)(wsp + off);         off += 8192;           // 16*256*2
    bf16_t* W1bp = (bf16_t*)(wsp + off);         off += 786432;         // 768*512*2
    bf16_t* W1tp = (bf16_t*)(wsp + off);         off += 1048576;        // 1024*512*2
    bf16_t* W2bp = (bf16_t*)(wsp + off);         off += 262144;         // 512*256*2
    bf16_t* W2tp = (bf16_t*)(wsp + off);         off += 262144;
    int* inv   = (int*)(wsp + off);              off += 262144;         // 65536*4
    int* lists = (int*)(wsp + off);              off += 229376;         // 57344*4
    int* cnts  = (int*)(wsp + off);              off += 64;             // total ~15.4 MB
    int* flag  = cnts + 8;

    hipMemsetAsync(cnts, 0, 64, stream);
    hipMemsetAsync(inv, 0xFF, 262144, stream);
    detect_dtype<<<1, 64, 0, stream>>>((const unsigned short*)comp_table, flag);
    // one merged prep dispatch: conv_op + pack_w x4 + scan_rows
    prep<<<4736, 256, 0, stream>>>(op_table, opb,
                                   W1b, W1bp, W1t, W1tp, W2b, W2bp, W2t, W2tp, flag,
                                   lvl2, lvl1, lvl0, tch, lists, cnts, inv);

    // level 2: lists t @0 / b @16384, cnts slot 0 -> slots base 0
    fused_level<<<513, 256, 0, stream>>>(lists + 0, lists + 16384, cnts + 0, lvl2,
        opids, lch, rch, tch, ne2, opb, comp_table, cid, inv, flag,
        W1tp, b1t, W2tp, b2t, W1bp, b1b, W2bp, b2b, gma, bta, 0, nullptr);
    // level 1: lists t @32768 / b @40960, cnts slot 1 -> slots base 16384
    fused_level<<<257, 256, 0, stream>>>(lists + 32768, lists + 40960, cnts + 2, lvl1,
        opids, lch, rch, tch, ne2, opb, comp_table, cid, inv, flag,
        W1tp, b1t, W2tp, b2t, W1bp, b1b, W2bp, b2b, gma, bta, 16384, nullptr);
    // level 0: lists t @49152 / b @53248, cnts slot 2 -> d_out
    fused_level<<<129, 256, 0, stream>>>(lists + 49152, lists + 53248, cnts + 4, lvl0,
        opids, lch, rch, tch, ne2, opb, comp_table, cid, inv, flag,
        W1tp, b1t, W2tp, b2t, W1bp, b1b, W2bp, b2b, gma, bta, 0, d_out);
}

// Round 9
// 239.068 us; speedup vs baseline: 2.4753x; 1.1586x over previous
//
#include <hip/hip_runtime.h>

typedef __bf16 bf16_t;
typedef __attribute__((ext_vector_type(8))) __bf16 bf16x8;
typedef __attribute__((ext_vector_type(4))) __bf16 bf16x4;
typedef __attribute__((ext_vector_type(4))) float f32x4;

// async global->LDS, 16B per lane; LDS dest = wave-uniform base + lane*16
#define GLL16(gsrc, ldst) __builtin_amdgcn_global_load_lds( \
    (const __attribute__((address_space(1))) void*)(gsrc),  \
    (__attribute__((address_space(3))) void*)(ldst), 16, 0, 0)
#define SBAR() __builtin_amdgcn_s_barrier()
#define SCHED0() __builtin_amdgcn_sched_barrier(0)

// ---------------- dtype detect: 1 = bf16 inputs, 0 = fp32 inputs.
__global__ void detect_dtype(const unsigned short* __restrict__ ct, int* __restrict__ flag) {
    if (threadIdx.x == 0 && blockIdx.x == 0) {
        int ok = 1;
        for (int i = 0; i < 16; i++) {
            int e = (ct[256 + i] >> 7) & 0xFF;
            ok &= (e >= 80 && e <= 126) ? 1 : 0;
        }
        *flag = ok;
    }
}

// ---------------- merged prep: conv_op + ctb + 4x pack_w(swizzled) + scan_rows
// blocks [0,16): op_table->bf16   [16,2016): comp_table->ctb bf16
// [2016,3552): W1b  [3552,5600): W1t  [5600,6112): W2b  [6112,6624): W2t
//   pack: [K][N] -> [K/32][N][32] bf16 with 16B-chunk swizzle gp = (kl>>3)^((n>>1)&3)
//   (GLL16 stages LDS linearly; read side applies qq^gx — R5-verified correct)
// [6624,6736): scan_rows (R0-verified math)
__global__ void prep(const void* __restrict__ op_table, bf16_t* __restrict__ opb,
                     const void* __restrict__ comp_table, bf16_t* __restrict__ ctb,
                     const void* __restrict__ W1b, bf16_t* __restrict__ W1bp,
                     const void* __restrict__ W1t, bf16_t* __restrict__ W1tp,
                     const void* __restrict__ W2b, bf16_t* __restrict__ W2bp,
                     const void* __restrict__ W2t, bf16_t* __restrict__ W2tp,
                     const int* __restrict__ flagp,
                     const int* __restrict__ lvl2, const int* __restrict__ lvl1,
                     const int* __restrict__ lvl0, const int* __restrict__ third,
                     int* __restrict__ lists, int* __restrict__ cnts,
                     int* __restrict__ inv) {
    int b = blockIdx.x, tid = threadIdx.x;
    if (b >= 6624) {
        int r = (b - 6624) * 256 + tid;   // covers exactly 28672
        int slot, lr, base_t, base_b;
        const int* lvl;
        if (r < 16384)      { slot = 0; lr = r;         lvl = lvl2; base_t = 0;     base_b = 16384; }
        else if (r < 24576) { slot = 1; lr = r - 16384; lvl = lvl1; base_t = 32768; base_b = 40960; }
        else                { slot = 2; lr = r - 24576; lvl = lvl0; base_t = 49152; base_b = 53248; }
        int node = lvl[lr];
        int tern = third[node] >= 0 ? 1 : 0;
        if (slot == 0)      inv[node] = lr;
        else if (slot == 1) inv[node] = 16384 + lr;

        unsigned long long bt = __ballot(tern);
        unsigned long long bb = __ballot(!tern);
        int lane = tid & 63;
        unsigned long long ltm = (1ull << lane) - 1ull;
        int post = __popcll(bt & ltm), posb = __popcll(bb & ltm);
        int baseT = 0, baseB = 0;
        if (lane == 0) {
            baseT = atomicAdd(&cnts[slot * 2 + 1], __popcll(bt));
            baseB = atomicAdd(&cnts[slot * 2 + 0], __popcll(bb));
        }
        baseT = __shfl(baseT, 0, 64);
        baseB = __shfl(baseB, 0, 64);
        lists[tern ? (base_t + baseT + post) : (base_b + baseB + posb)] = lr;
        return;
    }
    int isbf = *flagp;
    if (b < 16) {
        int i = b * 256 + tid;
        opb[i] = isbf ? ((const bf16_t*)op_table)[i] : (bf16_t)((const float*)op_table)[i];
        return;
    }
    if (b < 2016) {
        int i = (b - 16) * 256 + tid;
        ctb[i] = isbf ? ((const bf16_t*)comp_table)[i] : (bf16_t)((const float*)comp_table)[i];
        return;
    }
    const void* src; bf16_t* dst; int e0, Nmask, Nshift;
    if (b < 3552)      { src = W1b; dst = W1bp; e0 = (b - 2016) * 256; Nmask = 511; Nshift = 9; }
    else if (b < 5600) { src = W1t; dst = W1tp; e0 = (b - 3552) * 256; Nmask = 511; Nshift = 9; }
    else if (b < 6112) { src = W2b; dst = W2bp; e0 = (b - 5600) * 256; Nmask = 255; Nshift = 8; }
    else               { src = W2t; dst = W2tp; e0 = (b - 6112) * 256; Nmask = 255; Nshift = 8; }
    int e = e0 + tid;
    bf16_t v = isbf ? ((const bf16_t*)src)[e] : (bf16_t)((const float*)src)[e];
    int n = e & Nmask, k = e >> Nshift;
    int kc = k >> 5, kl = k & 31;
    int gp = (kl >> 3) ^ ((n >> 1) & 3);
    dst[(size_t)(((kc << Nshift) + n) << 5) + (gp << 3) + (kl & 7)] = v;
}

__device__ __forceinline__ void load8f(const bf16_t* ne2, const void* ct, int isbf,
                                       int invn, int cidn, int q, float* o) {
    if (invn >= 0) {
        bf16x8 v = *(const bf16x8*)(ne2 + (size_t)invn * 256 + q);
        for (int z = 0; z < 8; z++) o[z] = (float)v[z];
    } else if (isbf) {
        bf16x8 v = *(const bf16x8*)((const bf16_t*)ct + (size_t)cidn * 256 + q);
        for (int z = 0; z < 8; z++) o[z] = (float)v[z];
    } else {
        const float* fp = (const float*)ct + (size_t)cidn * 256 + q;
        f32x4 a = *(const f32x4*)fp, b = *(const f32x4*)(fp + 4);
        for (int z = 0; z < 4; z++) { o[z] = a[z]; o[z + 4] = b[z]; }
    }
}

__device__ __forceinline__ float ldparam(const void* p, int i, int isbf) {
    return isbf ? (float)((const bf16_t*)p)[i] : ((const float*)p)[i];
}

// ---------------- fused level kernel, M=32, 2 blocks/CU, counted-vmcnt dbuf pipeline
// LDS map (69632 B):
//   GEMM1: B1 dbuf [0,32K)+[32K,64K); A dbuf [64K,66K)+[66K,68K)
//   GELU/GEMM2: B2 dbuf [0,16K)+[16K,32K); H [32K,64K) (chunk-XOR swizzled)
//   epilogue: R float[32][256] at [0,32K); LN partials at [64K,...)
// Pipeline per iter: issue stage(k+1) -> s_waitcnt vmcnt(loads of stage(k+1)) [stage(k)
// landed, stage(k+1) stays in flight] -> s_barrier -> ds_read+MFMA -> s_barrier.
__global__ __launch_bounds__(256, 2) void fused_level(
    const int* __restrict__ list_t, const int* __restrict__ list_b,
    const int* __restrict__ cntpair, const int* __restrict__ lvl_idx,
    const int* __restrict__ op_ids, const int* __restrict__ lch,
    const int* __restrict__ rch, const int* __restrict__ tch,
    bf16_t* __restrict__ ne2, const bf16_t* __restrict__ opb,
    const void* __restrict__ ct, const bf16_t* __restrict__ ctb,
    const int* __restrict__ cid, const int* __restrict__ inv,
    const int* __restrict__ flagp,
    const bf16_t* __restrict__ W1tp, const void* __restrict__ b1t,
    const bf16_t* __restrict__ W2tp, const void* __restrict__ b2t,
    const bf16_t* __restrict__ W1bp, const void* __restrict__ b1b,
    const bf16_t* __restrict__ W2bp, const void* __restrict__ b2b,
    const void* __restrict__ gma, const void* __restrict__ bta,
    int slotBase, void* __restrict__ out)
{
    __shared__ __align__(1024) char smem[69632];

    const int tid = threadIdx.x;
    const int w = tid >> 6, lane = tid & 63, cc = lane & 15, qq = lane >> 4;
    const int gx = (cc >> 1) & 3;   // chunk XOR for packed-weight / A reads
    const int e7 = cc & 7;          // chunk XOR for H
    const int cnt_t = cntpair[1], cnt_b = cntpair[0];
    const int blocks_t = (cnt_t + 31) >> 5;
    int tern, base, cnt, K1c;
    const int* list;
    const bf16_t *W1p, *W2p;
    const void *b1, *b2;
    if ((int)blockIdx.x < blocks_t) {
        tern = 1; list = list_t; base = blockIdx.x * 32; cnt = cnt_t;
        W1p = W1tp; b1 = b1t; W2p = W2tp; b2 = b2t; K1c = 32;
    } else {
        tern = 0; list = list_b; base = (blockIdx.x - blocks_t) * 32; cnt = cnt_b;
        if (base >= cnt) return;
        W1p = W1bp; b1 = b1b; W2p = W2bp; b2 = b2b; K1c = 24;
    }
    const int act = min(32, cnt - base);
    const int isbf = *flagp;

    // ---- A-staging identity (tid<128): row = tid>>2, phys 16B chunk = tid&3
    int glA = 0, opSA = 0;
    int aInv0 = 0, aInv1 = 0, aInv2 = 0, aCid0 = 0, aCid1 = 0, aCid2 = 0;
    if (tid < 128) {
        int rowA = tid >> 2;
        glA = (tid & 3) ^ ((rowA >> 1) & 3);        // logical chunk this thread fetches
        int rA = list[base + min(rowA, act - 1)];
        int nA = lvl_idx[rA];
        opSA = op_ids[nA];
        int a0 = lch[nA], a1 = rch[nA];
        int a2 = tern ? tch[nA] : a0;
        aInv0 = inv[a0]; aInv1 = inv[a1]; aInv2 = inv[a2];
        aCid0 = aInv0 < 0 ? cid[a0] : 0;
        aCid1 = aInv1 < 0 ? cid[a1] : 0;
        aCid2 = aInv2 < 0 ? cid[a2] : 0;
    }

    // ---- residual identity: row ms = tid>>3, col group gs = tid&7 (R8 verbatim)
    const int ms = tid >> 3, gs = tid & 7;
    const int lr = list[base + min(ms, act - 1)];
    const int node = lvl_idx[lr];
    const int c0 = lch[node], c1 = rch[node];
    const int c2 = tern ? tch[node] : c0;
    int sInv[3] = {inv[c0], inv[c1], inv[c2]};
    int sCid[3];
    sCid[0] = sInv[0] < 0 ? cid[c0] : 0;
    sCid[1] = sInv[1] < 0 ? cid[c1] : 0;
    sCid[2] = sInv[2] < 0 ? cid[c2] : 0;

    // per-lane params for GEMM2 epilogue
    float b2f[4], gf[4], btf[4];
    for (int j = 0; j < 4; j++) {
        int col = (w + 4 * j) * 16 + cc;
        b2f[j] = ldparam(b2, col, isbf);
        gf[j] = ldparam(gma, col, isbf);
        btf[j] = ldparam(bta, col, isbf);
    }

    const f32x4 zf = {0.f, 0.f, 0.f, 0.f};
    f32x4 acc1[2][8];
    for (int m = 0; m < 2; m++) for (int j = 0; j < 8; j++) acc1[m][j] = zf;

    // ================= GEMM1 (swapped operands), dbuf + counted vmcnt =================
    // stage1(kc,bsel): 8 GLL16 B-slab (all threads) + 1 GLL16 A (waves 0,1)
#define STAGE1(kc_, bsel_) do {                                                   \
        const char* srcb_ = (const char*)W1p + ((size_t)(kc_) << 15);             \
        char* dstb_ = smem + ((bsel_) << 15);                                     \
        _Pragma("unroll")                                                         \
        for (int i_ = 0; i_ < 8; i_++) {                                          \
            int off_ = ((i_ << 2) + w) << 10;                                     \
            GLL16(srcb_ + off_ + (lane << 4), dstb_ + off_);                      \
        }                                                                         \
        if (w < 2) {                                                              \
            int colg_ = (kc_) * 32 + glA * 8;                                     \
            int piece_ = colg_ >> 8, po_ = colg_ & 255;                           \
            int iv_ = piece_ == 1 ? aInv0 : piece_ == 2 ? aInv1 : aInv2;          \
            int cd_ = piece_ == 1 ? aCid0 : piece_ == 2 ? aCid1 : aCid2;          \
            const bf16_t* s_ = piece_ == 0 ? opb + (size_t)opSA * 256             \
                : (iv_ >= 0 ? ne2 + (size_t)iv_ * 256 : ctb + (size_t)cd_ * 256); \
            GLL16(s_ + po_, smem + 65536 + ((bsel_) << 11) + (w << 10));          \
        }                                                                         \
    } while (0)

    STAGE1(0, 0);
    for (int kc = 0; kc < K1c; kc++) {
        const int cur = kc & 1;
        const bool more = kc + 1 < K1c;
        if (more) STAGE1(kc + 1, cur ^ 1);
        // wait: stage(kc) landed; stage(kc+1) (9 for waves 0-1, 8 for 2-3) stays in flight
        if (more) {
            if (w < 2) asm volatile("s_waitcnt vmcnt(9)" ::: "memory");
            else       asm volatile("s_waitcnt vmcnt(8)" ::: "memory");
        } else {
            asm volatile("s_waitcnt vmcnt(0)" ::: "memory");
        }
        SCHED0();
        SBAR();                     // buf[cur] complete for all waves
        SCHED0();
        const bf16_t* as = (const bf16_t*)(smem + 65536 + (cur << 11));
        const bf16_t* bs = (const bf16_t*)(smem + (cur << 15));
        bf16x8 af[2];
        for (int m = 0; m < 2; m++)
            af[m] = *(const bf16x8*)(as + (m * 16 + cc) * 32 + ((qq ^ gx) << 3));
        for (int j = 0; j < 8; j++) {
            bf16x8 bv = *(const bf16x8*)(bs + ((w + 4 * j) * 16 + cc) * 32 + ((qq ^ gx) << 3));
            for (int m = 0; m < 2; m++)
                acc1[m][j] = __builtin_amdgcn_mfma_f32_16x16x32_bf16(bv, af[m], acc1[m][j], 0, 0, 0);
        }
        SCHED0();
        SBAR();                     // all reads of buf[cur] done -> restageable
    }

    // ================= B2 slab 0 flies under bias + exact GELU -> H =================
#define STAGE2(kc_, bsel_) do {                                                   \
        const char* srcb_ = (const char*)W2p + ((size_t)(kc_) << 14);             \
        char* dstb_ = smem + ((bsel_) << 14);                                     \
        _Pragma("unroll")                                                         \
        for (int i_ = 0; i_ < 4; i_++) {                                          \
            int off_ = ((i_ << 2) + w) << 10;                                     \
            GLL16(srcb_ + off_ + (lane << 4), dstb_ + off_);                      \
        }                                                                         \
    } while (0)

    STAGE2(0, 0);
    {
        unsigned short* Hs = (unsigned short*)(smem + 32768);
        for (int j = 0; j < 8; j++) {
            float b1q[4];
            for (int r = 0; r < 4; r++) b1q[r] = ldparam(b1, (w + 4 * j) * 16 + qq * 4 + r, isbf);
            int c16 = ((w + 4 * j) << 1) + (qq >> 1);
            for (int m = 0; m < 2; m++) {
                int row = m * 16 + cc;
                bf16x4 hv;
                for (int r = 0; r < 4; r++) {
                    float v = acc1[m][j][r] + b1q[r];
                    hv[r] = (bf16_t)(0.5f * v * (1.0f + erff(v * 0.70710678118654752f)));
                }
                *(bf16x4*)(Hs + (row << 9) + ((c16 ^ e7) << 3) + ((qq & 1) << 2)) = hv;
            }
        }
    }

    // ================= GEMM2, dbuf + counted vmcnt =================
    f32x4 acc2[2][4];
    for (int m = 0; m < 2; m++) for (int j = 0; j < 4; j++) acc2[m][j] = zf;
    for (int kc = 0; kc < 16; kc++) {
        const int cur = kc & 1;
        const bool more = kc + 1 < 16;
        if (more) STAGE2(kc + 1, cur ^ 1);
        // lgkmcnt(0): own H ds_writes complete before barrier (first iter)
        if (more) asm volatile("s_waitcnt vmcnt(4) lgkmcnt(0)" ::: "memory");
        else      asm volatile("s_waitcnt vmcnt(0) lgkmcnt(0)" ::: "memory");
        SCHED0();
        SBAR();
        SCHED0();
        const unsigned short* Hs = (const unsigned short*)(smem + 32768);
        const bf16_t* bs = (const bf16_t*)(smem + (cur << 14));
        bf16x8 af[2];
        for (int m = 0; m < 2; m++)
            af[m] = *(const bf16x8*)(Hs + ((m * 16 + cc) << 9) + ((((kc << 2) + qq) ^ e7) << 3));
        for (int j = 0; j < 4; j++) {
            bf16x8 bv = *(const bf16x8*)(bs + ((w + 4 * j) * 16 + cc) * 32 + ((qq ^ gx) << 3));
            for (int m = 0; m < 2; m++)
                acc2[m][j] = __builtin_amdgcn_mfma_f32_16x16x32_bf16(af[m], bv, acc2[m][j], 0, 0, 0);
        }
        SCHED0();
        SBAR();
    }
    __syncthreads();                // settle before epilogue overlays

    // ---------- residual gather -> R float[32][256] at smem[0,32K)  (R8 verbatim math)
    {
        float* Rf = (float*)smem;
        int colb = gs * 32;
        for (int i = 0; i < 4; i++) {
            int q = colb + i * 8;
            float lv[8], rv[8], tv[8];
            load8f(ne2, ct, isbf, sInv[0], sCid[0], q, lv);
            load8f(ne2, ct, isbf, sInv[1], sCid[1], q, rv);
            if (tern) load8f(ne2, ct, isbf, sInv[2], sCid[2], q, tv);
            f32x4 s0, s1;
            if (tern) {
                for (int z = 0; z < 4; z++) {
                    s0[z] = (lv[z] + rv[z] + tv[z]) * (1.0f / 3.0f);
                    s1[z] = (lv[z + 4] + rv[z + 4] + tv[z + 4]) * (1.0f / 3.0f);
                }
            } else {
                for (int z = 0; z < 4; z++) {
                    s0[z] = lv[z] + rv[z];
                    s1[z] = lv[z + 4] + rv[z + 4];
                }
            }
            *(f32x4*)(Rf + ms * 256 + q) = s0;
            *(f32x4*)(Rf + ms * 256 + q + 4) = s1;
        }
    }
    __syncthreads();

    // ---------- x = gemm2 + b2 + R ; LayerNorm over 256 cols per row (R8 verbatim)
    float* partS = (float*)(smem + 65536); // [4][32]
    float* partQ = partS + 128;            // [4][32]
    float* muA   = partQ + 128;            // [32]
    float* rsA   = muA + 32;               // [32]
    const float* Rf = (const float*)smem;

    for (int m = 0; m < 2; m++) for (int r = 0; r < 4; r++) {
        int row = m * 16 + qq * 4 + r;
        float ps = 0.f, pq = 0.f;
        for (int j = 0; j < 4; j++) {
            int col = (w + 4 * j) * 16 + cc;
            float x = acc2[m][j][r] + b2f[j] + Rf[(row << 8) + col];
            acc2[m][j][r] = x;
            ps += x; pq += x * x;
        }
        for (int d = 1; d < 16; d <<= 1) {
            ps += __shfl_xor(ps, d, 64);
            pq += __shfl_xor(pq, d, 64);
        }
        if (cc == 0) { partS[w * 32 + row] = ps; partQ[w * 32 + row] = pq; }
    }
    __syncthreads();
    if (tid < 32) {
        float s  = partS[tid] + partS[32 + tid] + partS[64 + tid] + partS[96 + tid];
        float sq = partQ[tid] + partQ[32 + tid] + partQ[64 + tid] + partQ[96 + tid];
        float mu = s * (1.0f / 256.0f);
        float var = sq * (1.0f / 256.0f) - mu * mu;
        muA[tid] = mu;
        rsA[tid] = rsqrtf(fmaxf(var, 0.0f) + 1e-5f);
    }
    __syncthreads();

    for (int m = 0; m < 2; m++) for (int r = 0; r < 4; r++) {
        int row = m * 16 + qq * 4 + r;
        if (row >= act) continue;
        float mu = muA[row], rs = rsA[row];
        int lr2 = list[base + row];
        for (int j = 0; j < 4; j++) {
            int col = (w + 4 * j) * 16 + cc;
            float y = (acc2[m][j][r] - mu) * rs * gf[j] + btf[j];
            if (out) {
                if (isbf) ((bf16_t*)out)[(size_t)lr2 * 256 + col] = (bf16_t)y;
                else      ((float*)out)[(size_t)lr2 * 256 + col] = y;
            } else {
                ne2[(size_t)(slotBase + lr2) * 256 + col] = (bf16_t)y;
            }
        }
    }
#undef STAGE1
#undef STAGE2
}

extern "C" void kernel_launch(void* const* d_in, const int* in_sizes, int n_in,
                              void* d_out, int out_size, void* d_ws, size_t ws_size,
                              hipStream_t stream) {
    const int* cid    = (const int*)d_in[0];
    const int* opids  = (const int*)d_in[1];
    const int* lch    = (const int*)d_in[2];
    const int* rch    = (const int*)d_in[3];
    const int* tch    = (const int*)d_in[4];
    const int* lvl2   = (const int*)d_in[5];
    const int* lvl1   = (const int*)d_in[6];
    const int* lvl0   = (const int*)d_in[7];
    const void* comp_table = d_in[8];
    const void* op_table   = d_in[9];
    const void* W1b = d_in[10];
    const void* b1b = d_in[11];
    const void* W2b = d_in[12];
    const void* b2b = d_in[13];
    const void* W1t = d_in[14];
    const void* b1t = d_in[15];
    const void* W2t = d_in[16];
    const void* b2t = d_in[17];
    const void* gma = d_in[18];
    const void* bta = d_in[19];

    char* wsp = (char*)d_ws;
    bf16_t* ne2  = (bf16_t*)wsp;                 size_t off = 12582912; // 24576*256*2
    bf16_t* opb  = (bf16_t*)(wsp + off);         off += 8192;           // 16*256*2
    bf16_t* ctb  = (bf16_t*)(wsp + off);         off += 1024000;        // 2000*256*2
    bf16_t* W1bp = (bf16_t*)(wsp + off);         off += 786432;         // 768*512*2
    bf16_t* W1tp = (bf16_t*)(wsp + off);         off += 1048576;        // 1024*512*2
    bf16_t* W2bp = (bf16_t*)(wsp + off);         off += 262144;         // 512*256*2
    bf16_t* W2tp = (bf16_t*)(wsp + off);         off += 262144;
    int* inv   = (int*)(wsp + off);              off += 262144;         // 65536*4
    int* lists = (int*)(wsp + off);              off += 229376;         // 57344*4
    int* cnts  = (int*)(wsp + off);              off += 64;             // total ~16.5 MB
    int* flag  = cnts + 8;

    hipMemsetAsync(cnts, 0, 64, stream);
    hipMemsetAsync(inv, 0xFF, 262144, stream);
    detect_dtype<<<1, 64, 0, stream>>>((const unsigned short*)comp_table, flag);
    // one merged prep dispatch: conv_op + ctb + pack_w x4 + scan_rows
    prep<<<6736, 256, 0, stream>>>(op_table, opb, comp_table, ctb,
                                   W1b, W1bp, W1t, W1tp, W2b, W2bp, W2t, W2tp, flag,
                                   lvl2, lvl1, lvl0, tch, lists, cnts, inv);

    // level 2: lists t @0 / b @16384, cnts slot 0 -> slots base 0
    fused_level<<<513, 256, 0, stream>>>(lists + 0, lists + 16384, cnts + 0, lvl2,
        opids, lch, rch, tch, ne2, opb, comp_table, ctb, cid, inv, flag,
        W1tp, b1t, W2tp, b2t, W1bp, b1b, W2bp, b2b, gma, bta, 0, nullptr);
    // level 1: lists t @32768 / b @40960, cnts slot 1 -> slots base 16384
    fused_level<<<257, 256, 0, stream>>>(lists + 32768, lists + 40960, cnts + 2, lvl1,
        opids, lch, rch, tch, ne2, opb, comp_table, ctb, cid, inv, flag,
        W1tp, b1t, W2tp, b2t, W1bp, b1b, W2bp, b2b, gma, bta, 16384, nullptr);
    // level 0: lists t @49152 / b @53248, cnts slot 2 -> d_out
    fused_level<<<129, 256, 0, stream>>>(lists + 49152, lists + 53248, cnts + 4, lvl0,
        opids, lch, rch, tch, ne2, opb, comp_table, ctb, cid, inv, flag,
        W1tp, b1t, W2tp, b2t, W1bp, b1b, W2bp, b2b, gma, bta, 0, d_out);
}

// Round 10
// 216.905 us; speedup vs baseline: 2.7282x; 1.1022x over previous
//
#include <hip/hip_runtime.h>

typedef __bf16 bf16_t;
typedef __attribute__((ext_vector_type(8))) __bf16 bf16x8;
typedef __attribute__((ext_vector_type(4))) __bf16 bf16x4;
typedef __attribute__((ext_vector_type(4))) float f32x4;

// async global->LDS, 16B per lane; LDS dest = wave-uniform base + lane*16
#define GLL16(gsrc, ldst) __builtin_amdgcn_global_load_lds( \
    (const __attribute__((address_space(1))) void*)(gsrc),  \
    (__attribute__((address_space(3))) void*)(ldst), 16, 0, 0)
#define SBAR() __builtin_amdgcn_s_barrier()
#define SCHED0() __builtin_amdgcn_sched_barrier(0)

// ---------------- dtype detect: 1 = bf16 inputs, 0 = fp32 inputs.
__global__ void detect_dtype(const unsigned short* __restrict__ ct, int* __restrict__ flag) {
    if (threadIdx.x == 0 && blockIdx.x == 0) {
        int ok = 1;
        for (int i = 0; i < 16; i++) {
            int e = (ct[256 + i] >> 7) & 0xFF;
            ok &= (e >= 80 && e <= 126) ? 1 : 0;
        }
        *flag = ok;
    }
}

// ---------------- merged prep: conv_op + ctb + 4x pack_w(swizzled) + scan_rows
// (R9 verbatim — verified correct + fast)
__global__ void prep(const void* __restrict__ op_table, bf16_t* __restrict__ opb,
                     const void* __restrict__ comp_table, bf16_t* __restrict__ ctb,
                     const void* __restrict__ W1b, bf16_t* __restrict__ W1bp,
                     const void* __restrict__ W1t, bf16_t* __restrict__ W1tp,
                     const void* __restrict__ W2b, bf16_t* __restrict__ W2bp,
                     const void* __restrict__ W2t, bf16_t* __restrict__ W2tp,
                     const int* __restrict__ flagp,
                     const int* __restrict__ lvl2, const int* __restrict__ lvl1,
                     const int* __restrict__ lvl0, const int* __restrict__ third,
                     int* __restrict__ lists, int* __restrict__ cnts,
                     int* __restrict__ inv) {
    int b = blockIdx.x, tid = threadIdx.x;
    if (b >= 6624) {
        int r = (b - 6624) * 256 + tid;   // covers exactly 28672
        int slot, lr, base_t, base_b;
        const int* lvl;
        if (r < 16384)      { slot = 0; lr = r;         lvl = lvl2; base_t = 0;     base_b = 16384; }
        else if (r < 24576) { slot = 1; lr = r - 16384; lvl = lvl1; base_t = 32768; base_b = 40960; }
        else                { slot = 2; lr = r - 24576; lvl = lvl0; base_t = 49152; base_b = 53248; }
        int node = lvl[lr];
        int tern = third[node] >= 0 ? 1 : 0;
        if (slot == 0)      inv[node] = lr;
        else if (slot == 1) inv[node] = 16384 + lr;

        unsigned long long bt = __ballot(tern);
        unsigned long long bb = __ballot(!tern);
        int lane = tid & 63;
        unsigned long long ltm = (1ull << lane) - 1ull;
        int post = __popcll(bt & ltm), posb = __popcll(bb & ltm);
        int baseT = 0, baseB = 0;
        if (lane == 0) {
            baseT = atomicAdd(&cnts[slot * 2 + 1], __popcll(bt));
            baseB = atomicAdd(&cnts[slot * 2 + 0], __popcll(bb));
        }
        baseT = __shfl(baseT, 0, 64);
        baseB = __shfl(baseB, 0, 64);
        lists[tern ? (base_t + baseT + post) : (base_b + baseB + posb)] = lr;
        return;
    }
    int isbf = *flagp;
    if (b < 16) {
        int i = b * 256 + tid;
        opb[i] = isbf ? ((const bf16_t*)op_table)[i] : (bf16_t)((const float*)op_table)[i];
        return;
    }
    if (b < 2016) {
        int i = (b - 16) * 256 + tid;
        ctb[i] = isbf ? ((const bf16_t*)comp_table)[i] : (bf16_t)((const float*)comp_table)[i];
        return;
    }
    const void* src; bf16_t* dst; int e0, Nmask, Nshift;
    if (b < 3552)      { src = W1b; dst = W1bp; e0 = (b - 2016) * 256; Nmask = 511; Nshift = 9; }
    else if (b < 5600) { src = W1t; dst = W1tp; e0 = (b - 3552) * 256; Nmask = 511; Nshift = 9; }
    else if (b < 6112) { src = W2b; dst = W2bp; e0 = (b - 5600) * 256; Nmask = 255; Nshift = 8; }
    else               { src = W2t; dst = W2tp; e0 = (b - 6112) * 256; Nmask = 255; Nshift = 8; }
    int e = e0 + tid;
    bf16_t v = isbf ? ((const bf16_t*)src)[e] : (bf16_t)((const float*)src)[e];
    int n = e & Nmask, k = e >> Nshift;
    int kc = k >> 5, kl = k & 31;
    int gp = (kl >> 3) ^ ((n >> 1) & 3);
    dst[(size_t)(((kc << Nshift) + n) << 5) + (gp << 3) + (kl & 7)] = v;
}

__device__ __forceinline__ void load8f(const bf16_t* ne2, const void* ct, int isbf,
                                       int invn, int cidn, int q, float* o) {
    if (invn >= 0) {
        bf16x8 v = *(const bf16x8*)(ne2 + (size_t)invn * 256 + q);
        for (int z = 0; z < 8; z++) o[z] = (float)v[z];
    } else if (isbf) {
        bf16x8 v = *(const bf16x8*)((const bf16_t*)ct + (size_t)cidn * 256 + q);
        for (int z = 0; z < 8; z++) o[z] = (float)v[z];
    } else {
        const float* fp = (const float*)ct + (size_t)cidn * 256 + q;
        f32x4 a = *(const f32x4*)fp, b = *(const f32x4*)(fp + 4);
        for (int z = 0; z < 4; z++) { o[z] = a[z]; o[z + 4] = b[z]; }
    }
}

__device__ __forceinline__ float ldparam(const void* p, int i, int isbf) {
    return isbf ? (float)((const bf16_t*)p)[i] : ((const float*)p)[i];
}

// ---------------- fused level kernel, M=32, 512 threads (8 waves), 2 blocks/CU
// R9's counted-vmcnt dbuf pipeline with N-work split over 8 waves:
// acc1[2][4], acc2[2][2]; 4 GLL16/thread B1 stage; 16 waves/CU for latency hiding.
// LDS map (69632 B) identical to R9.
__global__ __launch_bounds__(512, 4) void fused_level(
    const int* __restrict__ list_t, const int* __restrict__ list_b,
    const int* __restrict__ cntpair, const int* __restrict__ lvl_idx,
    const int* __restrict__ op_ids, const int* __restrict__ lch,
    const int* __restrict__ rch, const int* __restrict__ tch,
    bf16_t* __restrict__ ne2, const bf16_t* __restrict__ opb,
    const void* __restrict__ ct, const bf16_t* __restrict__ ctb,
    const int* __restrict__ cid, const int* __restrict__ inv,
    const int* __restrict__ flagp,
    const bf16_t* __restrict__ W1tp, const void* __restrict__ b1t,
    const bf16_t* __restrict__ W2tp, const void* __restrict__ b2t,
    const bf16_t* __restrict__ W1bp, const void* __restrict__ b1b,
    const bf16_t* __restrict__ W2bp, const void* __restrict__ b2b,
    const void* __restrict__ gma, const void* __restrict__ bta,
    int slotBase, void* __restrict__ out)
{
    __shared__ __align__(1024) char smem[69632];

    const int tid = threadIdx.x;
    const int w = tid >> 6, lane = tid & 63, cc = lane & 15, qq = lane >> 4;
    const int gx = (cc >> 1) & 3;   // chunk XOR for packed-weight / A reads
    const int e7 = cc & 7;          // chunk XOR for H
    const int cnt_t = cntpair[1], cnt_b = cntpair[0];
    const int blocks_t = (cnt_t + 31) >> 5;
    int tern, base, cnt, K1c;
    const int* list;
    const bf16_t *W1p, *W2p;
    const void *b1, *b2;
    if ((int)blockIdx.x < blocks_t) {
        tern = 1; list = list_t; base = blockIdx.x * 32; cnt = cnt_t;
        W1p = W1tp; b1 = b1t; W2p = W2tp; b2 = b2t; K1c = 32;
    } else {
        tern = 0; list = list_b; base = (blockIdx.x - blocks_t) * 32; cnt = cnt_b;
        if (base >= cnt) return;
        W1p = W1bp; b1 = b1b; W2p = W2bp; b2 = b2b; K1c = 24;
    }
    const int act = min(32, cnt - base);
    const int isbf = *flagp;

    // ---- A-staging identity (tid<128 == waves 0,1): row = tid>>2, phys chunk = tid&3
    int glA = 0, opSA = 0;
    int aInv0 = 0, aInv1 = 0, aInv2 = 0, aCid0 = 0, aCid1 = 0, aCid2 = 0;
    if (tid < 128) {
        int rowA = tid >> 2;
        glA = (tid & 3) ^ ((rowA >> 1) & 3);        // logical chunk this thread fetches
        int rA = list[base + min(rowA, act - 1)];
        int nA = lvl_idx[rA];
        opSA = op_ids[nA];
        int a0 = lch[nA], a1 = rch[nA];
        int a2 = tern ? tch[nA] : a0;
        aInv0 = inv[a0]; aInv1 = inv[a1]; aInv2 = inv[a2];
        aCid0 = aInv0 < 0 ? cid[a0] : 0;
        aCid1 = aInv1 < 0 ? cid[a1] : 0;
        aCid2 = aInv2 < 0 ? cid[a2] : 0;
    }

    // ---- residual identity: row ms = tid>>4, col group gs = tid&15
    const int ms = tid >> 4, gs = tid & 15;
    const int lr = list[base + min(ms, act - 1)];
    const int node = lvl_idx[lr];
    const int c0 = lch[node], c1 = rch[node];
    const int c2 = tern ? tch[node] : c0;
    int sInv[3] = {inv[c0], inv[c1], inv[c2]};
    int sCid[3];
    sCid[0] = sInv[0] < 0 ? cid[c0] : 0;
    sCid[1] = sInv[1] < 0 ? cid[c1] : 0;
    sCid[2] = sInv[2] < 0 ? cid[c2] : 0;

    // per-lane params for GEMM2 epilogue: cols (w+8j)*16+cc, j=0..1
    float b2f[2], gf[2], btf[2];
    for (int j = 0; j < 2; j++) {
        int col = (w + 8 * j) * 16 + cc;
        b2f[j] = ldparam(b2, col, isbf);
        gf[j] = ldparam(gma, col, isbf);
        btf[j] = ldparam(bta, col, isbf);
    }

    const f32x4 zf = {0.f, 0.f, 0.f, 0.f};
    f32x4 acc1[2][4];
    for (int m = 0; m < 2; m++) for (int j = 0; j < 4; j++) acc1[m][j] = zf;

    // ================= GEMM1 (swapped operands), dbuf + counted vmcnt =================
    // B1 32KB = 2048 chunks; 512 threads x 4; A staged by waves 0,1.
#define STAGE1(kc_, bsel_) do {                                                   \
        const char* srcb_ = (const char*)W1p + ((size_t)(kc_) << 15);             \
        char* dstb_ = smem + ((bsel_) << 15);                                     \
        _Pragma("unroll")                                                         \
        for (int i_ = 0; i_ < 4; i_++) {                                          \
            int off_ = ((i_ << 3) + w) << 10;                                     \
            GLL16(srcb_ + off_ + (lane << 4), dstb_ + off_);                      \
        }                                                                         \
        if (w < 2) {                                                              \
            int colg_ = (kc_) * 32 + glA * 8;                                     \
            int piece_ = colg_ >> 8, po_ = colg_ & 255;                           \
            int iv_ = piece_ == 1 ? aInv0 : piece_ == 2 ? aInv1 : aInv2;          \
            int cd_ = piece_ == 1 ? aCid0 : piece_ == 2 ? aCid1 : aCid2;          \
            const bf16_t* s_ = piece_ == 0 ? opb + (size_t)opSA * 256             \
                : (iv_ >= 0 ? ne2 + (size_t)iv_ * 256 : ctb + (size_t)cd_ * 256); \
            GLL16(s_ + po_, smem + 65536 + ((bsel_) << 11) + (w << 10));          \
        }                                                                         \
    } while (0)

    STAGE1(0, 0);
    for (int kc = 0; kc < K1c; kc++) {
        const int cur = kc & 1;
        const bool more = kc + 1 < K1c;
        if (more) STAGE1(kc + 1, cur ^ 1);
        // wait: stage(kc) landed; stage(kc+1) (5 for waves 0-1, 4 for 2-7) in flight
        if (more) {
            if (w < 2) asm volatile("s_waitcnt vmcnt(5)" ::: "memory");
            else       asm volatile("s_waitcnt vmcnt(4)" ::: "memory");
        } else {
            asm volatile("s_waitcnt vmcnt(0)" ::: "memory");
        }
        SCHED0();
        SBAR();                     // buf[cur] complete for all waves
        SCHED0();
        const bf16_t* as = (const bf16_t*)(smem + 65536 + (cur << 11));
        const bf16_t* bs = (const bf16_t*)(smem + (cur << 15));
        bf16x8 af[2];
        for (int m = 0; m < 2; m++)
            af[m] = *(const bf16x8*)(as + (m * 16 + cc) * 32 + ((qq ^ gx) << 3));
        __builtin_amdgcn_s_setprio(1);
        for (int j = 0; j < 4; j++) {
            bf16x8 bv = *(const bf16x8*)(bs + ((w + 8 * j) * 16 + cc) * 32 + ((qq ^ gx) << 3));
            for (int m = 0; m < 2; m++)
                acc1[m][j] = __builtin_amdgcn_mfma_f32_16x16x32_bf16(bv, af[m], acc1[m][j], 0, 0, 0);
        }
        __builtin_amdgcn_s_setprio(0);
        SCHED0();
        SBAR();                     // all reads of buf[cur] done -> restageable
    }

    // ================= B2 slab 0 flies under bias + exact GELU -> H =================
#define STAGE2(kc_, bsel_) do {                                                   \
        const char* srcb_ = (const char*)W2p + ((size_t)(kc_) << 14);             \
        char* dstb_ = smem + ((bsel_) << 14);                                     \
        _Pragma("unroll")                                                         \
        for (int i_ = 0; i_ < 2; i_++) {                                          \
            int off_ = ((i_ << 3) + w) << 10;                                     \
            GLL16(srcb_ + off_ + (lane << 4), dstb_ + off_);                      \
        }                                                                         \
    } while (0)

    STAGE2(0, 0);
    {
        unsigned short* Hs = (unsigned short*)(smem + 32768);
        for (int j = 0; j < 4; j++) {
            float b1q[4];
            for (int r = 0; r < 4; r++) b1q[r] = ldparam(b1, (w + 8 * j) * 16 + qq * 4 + r, isbf);
            int c16 = ((w + 8 * j) << 1) + (qq >> 1);
            for (int m = 0; m < 2; m++) {
                int row = m * 16 + cc;
                bf16x4 hv;
                for (int r = 0; r < 4; r++) {
                    float v = acc1[m][j][r] + b1q[r];
                    hv[r] = (bf16_t)(0.5f * v * (1.0f + erff(v * 0.70710678118654752f)));
                }
                *(bf16x4*)(Hs + (row << 9) + ((c16 ^ e7) << 3) + ((qq & 1) << 2)) = hv;
            }
        }
    }

    // ================= GEMM2, dbuf + counted vmcnt =================
    f32x4 acc2[2][2];
    for (int m = 0; m < 2; m++) for (int j = 0; j < 2; j++) acc2[m][j] = zf;
    for (int kc = 0; kc < 16; kc++) {
        const int cur = kc & 1;
        const bool more = kc + 1 < 16;
        if (more) STAGE2(kc + 1, cur ^ 1);
        if (more) asm volatile("s_waitcnt vmcnt(2) lgkmcnt(0)" ::: "memory");
        else      asm volatile("s_waitcnt vmcnt(0) lgkmcnt(0)" ::: "memory");
        SCHED0();
        SBAR();
        SCHED0();
        const unsigned short* Hs = (const unsigned short*)(smem + 32768);
        const bf16_t* bs = (const bf16_t*)(smem + (cur << 14));
        bf16x8 af[2];
        for (int m = 0; m < 2; m++)
            af[m] = *(const bf16x8*)(Hs + ((m * 16 + cc) << 9) + ((((kc << 2) + qq) ^ e7) << 3));
        __builtin_amdgcn_s_setprio(1);
        for (int j = 0; j < 2; j++) {
            bf16x8 bv = *(const bf16x8*)(bs + ((w + 8 * j) * 16 + cc) * 32 + ((qq ^ gx) << 3));
            for (int m = 0; m < 2; m++)
                acc2[m][j] = __builtin_amdgcn_mfma_f32_16x16x32_bf16(af[m], bv, acc2[m][j], 0, 0, 0);
        }
        __builtin_amdgcn_s_setprio(0);
        SCHED0();
        SBAR();
    }
    __syncthreads();                // settle before epilogue overlays

    // ---------- residual gather -> R float[32][256] at smem[0,32K)
    {
        float* Rf = (float*)smem;
        int colb = gs * 16;
        for (int i = 0; i < 2; i++) {
            int q = colb + i * 8;
            float lv[8], rv[8], tv[8];
            load8f(ne2, ct, isbf, sInv[0], sCid[0], q, lv);
            load8f(ne2, ct, isbf, sInv[1], sCid[1], q, rv);
            if (tern) load8f(ne2, ct, isbf, sInv[2], sCid[2], q, tv);
            f32x4 s0, s1;
            if (tern) {
                for (int z = 0; z < 4; z++) {
                    s0[z] = (lv[z] + rv[z] + tv[z]) * (1.0f / 3.0f);
                    s1[z] = (lv[z + 4] + rv[z + 4] + tv[z + 4]) * (1.0f / 3.0f);
                }
            } else {
                for (int z = 0; z < 4; z++) {
                    s0[z] = lv[z] + rv[z];
                    s1[z] = lv[z + 4] + rv[z + 4];
                }
            }
            *(f32x4*)(Rf + ms * 256 + q) = s0;
            *(f32x4*)(Rf + ms * 256 + q + 4) = s1;
        }
    }
    __syncthreads();

    // ---------- x = gemm2 + b2 + R ; LayerNorm over 256 cols per row
    float* partS = (float*)(smem + 65536); // [8][32]
    float* partQ = partS + 256;            // [8][32]
    float* muA   = partQ + 256;            // [32]
    float* rsA   = muA + 32;               // [32]
    const float* Rf = (const float*)smem;

    for (int m = 0; m < 2; m++) for (int r = 0; r < 4; r++) {
        int row = m * 16 + qq * 4 + r;
        float ps = 0.f, pq = 0.f;
        for (int j = 0; j < 2; j++) {
            int col = (w + 8 * j) * 16 + cc;
            float x = acc2[m][j][r] + b2f[j] + Rf[(row << 8) + col];
            acc2[m][j][r] = x;
            ps += x; pq += x * x;
        }
        for (int d = 1; d < 16; d <<= 1) {
            ps += __shfl_xor(ps, d, 64);
            pq += __shfl_xor(pq, d, 64);
        }
        if (cc == 0) { partS[w * 32 + row] = ps; partQ[w * 32 + row] = pq; }
    }
    __syncthreads();
    if (tid < 32) {
        float s = 0.f, sq = 0.f;
        for (int i = 0; i < 8; i++) {
            s  += partS[i * 32 + tid];
            sq += partQ[i * 32 + tid];
        }
        float mu = s * (1.0f / 256.0f);
        float var = sq * (1.0f / 256.0f) - mu * mu;
        muA[tid] = mu;
        rsA[tid] = rsqrtf(fmaxf(var, 0.0f) + 1e-5f);
    }
    __syncthreads();

    for (int m = 0; m < 2; m++) for (int r = 0; r < 4; r++) {
        int row = m * 16 + qq * 4 + r;
        if (row >= act) continue;
        float mu = muA[row], rs = rsA[row];
        int lr2 = list[base + row];
        for (int j = 0; j < 2; j++) {
            int col = (w + 8 * j) * 16 + cc;
            float y = (acc2[m][j][r] - mu) * rs * gf[j] + btf[j];
            if (out) {
                if (isbf) ((bf16_t*)out)[(size_t)lr2 * 256 + col] = (bf16_t)y;
                else      ((float*)out)[(size_t)lr2 * 256 + col] = y;
            } else {
                ne2[(size_t)(slotBase + lr2) * 256 + col] = (bf16_t)y;
            }
        }
    }
#undef STAGE1
#undef STAGE2
}

extern "C" void kernel_launch(void* const* d_in, const int* in_sizes, int n_in,
                              void* d_out, int out_size, void* d_ws, size_t ws_size,
                              hipStream_t stream) {
    const int* cid    = (const int*)d_in[0];
    const int* opids  = (const int*)d_in[1];
    const int* lch    = (const int*)d_in[2];
    const int* rch    = (const int*)d_in[3];
    const int* tch    = (const int*)d_in[4];
    const int* lvl2   = (const int*)d_in[5];
    const int* lvl1   = (const int*)d_in[6];
    const int* lvl0   = (const int*)d_in[7];
    const void* comp_table = d_in[8];
    const void* op_table   = d_in[9];
    const void* W1b = d_in[10];
    const void* b1b = d_in[11];
    const void* W2b = d_in[12];
    const void* b2b = d_in[13];
    const void* W1t = d_in[14];
    const void* b1t = d_in[15];
    const void* W2t = d_in[16];
    const void* b2t = d_in[17];
    const void* gma = d_in[18];
    const void* bta = d_in[19];

    char* wsp = (char*)d_ws;
    bf16_t* ne2  = (bf16_t*)wsp;                 size_t off = 12582912; // 24576*256*2
    bf16_t* opb  = (bf16_t*)(wsp + off);         off += 8192;           // 16*256*2
    bf16_t* ctb  = (bf16_t*)(wsp + off);         off += 1024000;        // 2000*256*2
    bf16_t* W1bp = (bf16_t*)(wsp + off);         off += 786432;         // 768*512*2
    bf16_t* W1tp = (bf16_t*)(wsp + off);         off += 1048576;        // 1024*512*2
    bf16_t* W2bp = (bf16_t*)(wsp + off);         off += 262144;         // 512*256*2
    bf16_t* W2tp = (bf16_t*)(wsp + off);         off += 262144;
    int* inv   = (int*)(wsp + off);              off += 262144;         // 65536*4
    int* lists = (int*)(wsp + off);              off += 229376;         // 57344*4
    int* cnts  = (int*)(wsp + off);              off += 64;             // total ~16.5 MB
    int* flag  = cnts + 8;

    hipMemsetAsync(cnts, 0, 64, stream);
    hipMemsetAsync(inv, 0xFF, 262144, stream);
    detect_dtype<<<1, 64, 0, stream>>>((const unsigned short*)comp_table, flag);
    // one merged prep dispatch: conv_op + ctb + pack_w x4 + scan_rows
    prep<<<6736, 256, 0, stream>>>(op_table, opb, comp_table, ctb,
                                   W1b, W1bp, W1t, W1tp, W2b, W2bp, W2t, W2tp, flag,
                                   lvl2, lvl1, lvl0, tch, lists, cnts, inv);

    // level 2: lists t @0 / b @16384, cnts slot 0 -> slots base 0
    fused_level<<<513, 512, 0, stream>>>(lists + 0, lists + 16384, cnts + 0, lvl2,
        opids, lch, rch, tch, ne2, opb, comp_table, ctb, cid, inv, flag,
        W1tp, b1t, W2tp, b2t, W1bp, b1b, W2bp, b2b, gma, bta, 0, nullptr);
    // level 1: lists t @32768 / b @40960, cnts slot 1 -> slots base 16384
    fused_level<<<257, 512, 0, stream>>>(lists + 32768, lists + 40960, cnts + 2, lvl1,
        opids, lch, rch, tch, ne2, opb, comp_table, ctb, cid, inv, flag,
        W1tp, b1t, W2tp, b2t, W1bp, b1b, W2bp, b2b, gma, bta, 16384, nullptr);
    // level 0: lists t @49152 / b @53248, cnts slot 2 -> d_out
    fused_level<<<129, 512, 0, stream>>>(lists + 49152, lists + 53248, cnts + 4, lvl0,
        opids, lch, rch, tch, ne2, opb, comp_table, ctb, cid, inv, flag,
        W1tp, b1t, W2tp, b2t, W1bp, b1b, W2bp, b2b, gma, bta, 0, d_out);
}